// Round 1
// baseline (3563.479 us; speedup 1.0000x reference)
//
#include <hip/hip_runtime.h>

#define CC 128
#define HH 128
#define WW 128
#define DH 64
#define DW 64
#define LTOT 4096          // DH*DW patches / fg positions
#define K1 1152            // CC*3*3
#define K2 2048            // CC*4*4
#define SCALE_F 10.0f

// ---------------- im2col: 3x3 patches of downsampled (stride-2) image ----------------
// dst[k][q] (K-major, 1152 x 4096), k = c*9+di*3+dj, q = qy*64+qx
__global__ void im2col_k3_kernel(const float* __restrict__ src, float* __restrict__ dst) {
    int idx = blockIdx.x * blockDim.x + threadIdx.x;   // K1*LTOT threads exactly
    int q = idx & (LTOT - 1);
    int k = idx >> 12;
    int qx = q & 63, qy = q >> 6;
    int dj = k % 3, t = k / 3;
    int di = t % 3, c = t / 3;
    int yy = qy + di - 1, xx = qx + dj - 1;
    float v = 0.f;
    if (yy >= 0 && yy < DH && xx >= 0 && xx < DW)
        v = src[((size_t)c * HH + (yy << 1)) * WW + (xx << 1)];
    dst[idx] = v;
}

// ---------------- im2col: raw 4x4 stride-2 patches of full-res b ----------------
// dst[p][m] (4096 x 2048), m = c*16 + kd*4 + ke, covering rows 2*py-1+kd (zero-pad)
__global__ void im2col_raw_kernel(const float* __restrict__ src, float* __restrict__ dst) {
    int idx = blockIdx.x * blockDim.x + threadIdx.x;   // LTOT*K2 threads exactly
    int m = idx & (K2 - 1);
    int p = idx >> 11;
    int px = p & 63, py = p >> 6;
    int ke = m & 3, kd = (m >> 2) & 3, c = m >> 4;
    int yy = 2 * py - 1 + kd, xx = 2 * px - 1 + ke;
    float v = 0.f;
    if (yy >= 0 && yy < HH && xx >= 0 && xx < WW)
        v = src[((size_t)c * HH + yy) * WW + xx];
    dst[idx] = v;
}

// ---------------- per-pixel sum of squares over channels (on downsampled b) ----------------
__global__ void ssq_kernel(const float* __restrict__ b, float* __restrict__ ssq) {
    int p = blockIdx.x * blockDim.x + threadIdx.x;     // 4096
    int px = p & 63, py = p >> 6;
    float s = 0.f;
    for (int c = 0; c < CC; ++c) {
        float v = b[((size_t)c * HH + 2 * py) * WW + 2 * px];
        s += v * v;
    }
    ssq[p] = s;
}

// ---------------- patch inverse norm + mask gate ----------------
__global__ void norm_mm_kernel(const float* __restrict__ ssq, const float* __restrict__ mask,
                               float* __restrict__ inv_norm, float* __restrict__ mmv) {
    int p = blockIdx.x * blockDim.x + threadIdx.x;     // 4096
    int px = p & 63, py = p >> 6;
    float s = 0.f, ms = 0.f;
    for (int di = -1; di <= 1; ++di)
        for (int dj = -1; dj <= 1; ++dj) {
            int y = py + di, x = px + dj;
            if (y >= 0 && y < DH && x >= 0 && x < DW) {
                s += ssq[y * 64 + x];
                ms += mask[(size_t)(2 * y) * WW + 2 * x];  // mask downsampled ::2
            }
        }
    float n = sqrtf(s);
    if (n < 1e-4f) n = 1e-4f;
    inv_norm[p] = 1.f / n;
    mmv[p] = (ms == 0.f) ? 1.f : 0.f;
}

// ---------------- fp32 tiled GEMM, both operands K-major ----------------
// C[m][n] = scale(m) * sum_k Aop[k][m] * Bop[k][n];  M,N mult of 128, K mult of 8
__global__ __launch_bounds__(256) void gemm_kmajor(
    const float* __restrict__ Aop, const float* __restrict__ Bop,
    float* __restrict__ C, const float* __restrict__ rowscale,
    int M, int N, int K)
{
    __shared__ float As[8][128];
    __shared__ float Bs[8][128];
    int bm = blockIdx.y * 128, bn = blockIdx.x * 128;
    int tid = threadIdx.x;
    int tx = tid & 15, ty = tid >> 4;
    int lr = tid >> 5, lc = (tid & 31) << 2;
    float acc[8][8];
#pragma unroll
    for (int i = 0; i < 8; ++i)
#pragma unroll
        for (int j = 0; j < 8; ++j) acc[i][j] = 0.f;

    for (int k0 = 0; k0 < K; k0 += 8) {
        float4 av = *(const float4*)(Aop + (size_t)(k0 + lr) * M + bm + lc);
        float4 bv = *(const float4*)(Bop + (size_t)(k0 + lr) * N + bn + lc);
        *(float4*)&As[lr][lc] = av;
        *(float4*)&Bs[lr][lc] = bv;
        __syncthreads();
#pragma unroll
        for (int kk = 0; kk < 8; ++kk) {
            float a[8], b[8];
#pragma unroll
            for (int i = 0; i < 4; ++i) {
                a[i]     = As[kk][(ty << 2) + i];
                a[i + 4] = As[kk][64 + (ty << 2) + i];
                b[i]     = Bs[kk][(tx << 2) + i];
                b[i + 4] = Bs[kk][64 + (tx << 2) + i];
            }
#pragma unroll
            for (int i = 0; i < 8; ++i)
#pragma unroll
                for (int j = 0; j < 8; ++j)
                    acc[i][j] += a[i] * b[j];
        }
        __syncthreads();
    }

#pragma unroll
    for (int i = 0; i < 8; ++i) {
        int m = bm + ((i < 4) ? ((ty << 2) + i) : (64 + (ty << 2) + i - 4));
        float sc = rowscale ? rowscale[m] : 1.f;
        float4 v0 = make_float4(acc[i][0] * sc, acc[i][1] * sc, acc[i][2] * sc, acc[i][3] * sc);
        float4 v1 = make_float4(acc[i][4] * sc, acc[i][5] * sc, acc[i][6] * sc, acc[i][7] * sc);
        *(float4*)(C + (size_t)m * N + bn + (tx << 2)) = v0;
        *(float4*)(C + (size_t)m * N + bn + 64 + (tx << 2)) = v1;
    }
}

// ---------------- fuse 1: out[l][p] = sum_d in[l+d][p+d] on flat 4096x4096, zero-pad ----------------
__global__ void fuse1_kernel(const float* __restrict__ A, float* __restrict__ O) {
    int idx = blockIdx.x * blockDim.x + threadIdx.x;   // LTOT*LTOT
    int P = idx & (LTOT - 1);
    int Lr = idx >> 12;
    float s = 0.f;
#pragma unroll
    for (int d = -1; d <= 1; ++d) {
        int r = Lr + d, c = P + d;
        if (r >= 0 && r < LTOT && c >= 0 && c < LTOT)
            s += A[(size_t)r * LTOT + c];
    }
    O[idx] = s;
}

// ---------------- fuse 2: same conv but in transposed (bx-major / fx-major) flat layout ----------------
__global__ void fuse2_kernel(const float* __restrict__ A, float* __restrict__ O) {
    int idx = blockIdx.x * blockDim.x + threadIdx.x;   // LTOT*LTOT
    int P = idx & (LTOT - 1);
    int Lr = idx >> 12;
    int by = Lr >> 6, bx = Lr & 63;
    int fy = P >> 6,  fx = P & 63;
    int rbase = bx * 64 + by;
    int cbase = fx * 64 + fy;
    float s = 0.f;
#pragma unroll
    for (int d = -1; d <= 1; ++d) {
        int r = rbase + d, c = cbase + d;
        if (r >= 0 && r < LTOT && c >= 0 && c < LTOT) {
            int L2 = (r & 63) * 64 + (r >> 6);
            int P2 = (c & 63) * 64 + (c >> 6);
            s += A[(size_t)L2 * LTOT + P2];
        }
    }
    O[idx] = s;
}

// ---------------- column softmax over the 4096 patch axis (in place) ----------------
// logits = A * mm[l] * 10 ; out = softmax_col(logits) * mm[l]
__global__ __launch_bounds__(256) void softmax_kernel(float* __restrict__ A, const float* __restrict__ mmv) {
    __shared__ float red[4][64];
    int tid = threadIdx.x;
    int lane = tid & 63;
    int col = blockIdx.x * 64 + lane;
    int seg = tid >> 6;
    int l0 = seg * 1024, l1 = l0 + 1024;

    float mx = -3.4e38f;
    for (int l = l0; l < l1; ++l) {
        float v = A[(size_t)l * LTOT + col] * mmv[l] * SCALE_F;
        mx = fmaxf(mx, v);
    }
    red[seg][lane] = mx;
    __syncthreads();
    float gmx = fmaxf(fmaxf(red[0][lane], red[1][lane]),
                      fmaxf(red[2][lane], red[3][lane]));
    __syncthreads();

    float s = 0.f;
    for (int l = l0; l < l1; ++l) {
        float v = A[(size_t)l * LTOT + col] * mmv[l] * SCALE_F;
        s += __expf(v - gmx);
    }
    red[seg][lane] = s;
    __syncthreads();
    float gs = red[0][lane] + red[1][lane] + red[2][lane] + red[3][lane];
    float inv = 1.f / gs;

    for (int l = l0; l < l1; ++l) {
        size_t o = (size_t)l * LTOT + col;
        float v = A[o] * mmv[l] * SCALE_F;
        A[o] = __expf(v - gmx) * inv * mmv[l];
    }
}

// ---------------- overlap-add of weighted 4x4 patches (stride 2), /4 ----------------
// C2[q][m2] with q=(oy,ox), m2 = c*16 + kd*4 + ke; out[c][y][x]
__global__ void output_kernel(const float* __restrict__ C2, float* __restrict__ out) {
    int idx = blockIdx.x * blockDim.x + threadIdx.x;   // CC*HH*WW
    int x = idx & 127;
    int y = (idx >> 7) & 127;
    int c = idx >> 14;
    int oylo = max(0, (y - 1) >> 1), oyhi = min(63, (y + 1) >> 1);
    int oxlo = max(0, (x - 1) >> 1), oxhi = min(63, (x + 1) >> 1);
    float s = 0.f;
    for (int oy = oylo; oy <= oyhi; ++oy)
        for (int ox = oxlo; ox <= oxhi; ++ox) {
            int kd = y - 2 * oy + 1;
            int ke = x - 2 * ox + 1;
            s += C2[(size_t)(oy * 64 + ox) * K2 + c * 16 + kd * 4 + ke];
        }
    out[idx] = s * 0.25f;
}

extern "C" void kernel_launch(void* const* d_in, const int* in_sizes, int n_in,
                              void* d_out, int out_size, void* d_ws, size_t ws_size,
                              hipStream_t stream) {
    (void)in_sizes; (void)n_in; (void)out_size; (void)ws_size;
    const float* f    = (const float*)d_in[0];
    const float* b    = (const float*)d_in[1];
    const float* mask = (const float*)d_in[2];
    float* out = (float*)d_out;

    char* ws = (char*)d_ws;
    size_t off = 0;
    auto alloc = [&](size_t bytes) -> float* {
        float* p = (float*)(ws + off);
        off += (bytes + 255) & ~(size_t)255;
        return p;
    };
    float* A    = alloc((size_t)LTOT * LTOT * 4);   // 64 MB scores / attention
    float* Atmp = alloc((size_t)LTOT * LTOT * 4);   // 64 MB fuse ping-pong, then C2 (32 MB)
    float* Ft   = alloc((size_t)K1 * LTOT * 4);     // 18 MB f patches (K-major)
    float* Wdt  = alloc((size_t)K1 * LTOT * 4);     // 18 MB bd patches (K-major)
    float* ssq  = alloc(LTOT * 4);
    float* invn = alloc(LTOT * 4);
    float* mmv  = alloc(LTOT * 4);
    float* Wraw = Ft;   // 32 MB, reuses Ft+Wdt space after GEMM1 (36 MB available)

    for (int bi = 0; bi < 2; ++bi) {
        const float* fb = f + (size_t)bi * CC * HH * WW;
        const float* bb = b + (size_t)bi * CC * HH * WW;

        im2col_k3_kernel<<<K1 * LTOT / 256, 256, 0, stream>>>(fb, Ft);
        im2col_k3_kernel<<<K1 * LTOT / 256, 256, 0, stream>>>(bb, Wdt);
        ssq_kernel<<<LTOT / 256, 256, 0, stream>>>(bb, ssq);
        norm_mm_kernel<<<LTOT / 256, 256, 0, stream>>>(ssq, mask, invn, mmv);

        // A[p][q] = invn[p] * sum_k Wdt[k][p] * Ft[k][q]
        gemm_kmajor<<<dim3(LTOT / 128, LTOT / 128), 256, 0, stream>>>(
            Wdt, Ft, A, invn, LTOT, LTOT, K1);

        fuse1_kernel<<<(size_t)LTOT * LTOT / 256, 256, 0, stream>>>(A, Atmp);
        fuse2_kernel<<<(size_t)LTOT * LTOT / 256, 256, 0, stream>>>(Atmp, A);

        im2col_raw_kernel<<<(size_t)LTOT * K2 / 256, 256, 0, stream>>>(bb, Wraw);

        softmax_kernel<<<LTOT / 64, 256, 0, stream>>>(A, mmv);

        // C2[q][m2] = sum_p A[p][q] * Wraw[p][m2]
        gemm_kmajor<<<dim3(K2 / 128, LTOT / 128), 256, 0, stream>>>(
            A, Wraw, Atmp, nullptr, LTOT, K2, LTOT);

        output_kernel<<<CC * HH * WW / 256, 256, 0, stream>>>(Atmp, out + (size_t)bi * CC * HH * WW);
    }
}

// Round 2
// 1593.758 us; speedup vs baseline: 2.2359x; 2.2359x over previous
//
#include <hip/hip_runtime.h>

#define CC 128
#define HH 128
#define WW 128
#define DH 64
#define DW 64
#define LTOT 4096          // DH*DW patches / fg positions
#define K1 1152            // CC*3*3
#define K1S 3456           // 3*K1 split-concat K for GEMM1
#define K2 2048            // CC*4*4
#define SCALE_F 10.0f

typedef __attribute__((ext_vector_type(8))) short short8;
typedef __attribute__((ext_vector_type(4))) float f32x4;

// ---- bf16 helpers (RNE) ----
__device__ __forceinline__ unsigned short f2bf(float x) {
    union { float f; unsigned u; } v; v.f = x;
    unsigned r = v.u + 0x7fffu + ((v.u >> 16) & 1u);
    return (unsigned short)(r >> 16);
}
__device__ __forceinline__ float bf2f(unsigned short b) {
    union { unsigned u; float f; } v; v.u = ((unsigned)b) << 16;
    return v.f;
}

#define GLDS16(g, l) __builtin_amdgcn_global_load_lds( \
    (const __attribute__((address_space(1))) void*)(g), \
    (__attribute__((address_space(3))) void*)(l), 16, 0, 0)

// ---------------- im2col + fp32->bf16 split, M-major [p][3456] ----------------
// segments: lo_in_seg1 ? [hi, lo, hi] : [hi, hi, lo]
__global__ __launch_bounds__(256) void im2col_split_kernel(
    const float* __restrict__ src, unsigned short* __restrict__ dst, int lo_in_seg1)
{
    int p = blockIdx.x;                 // 4096 blocks
    int px = p & 63, py = p >> 6;
    size_t base = (size_t)p * K1S;
    for (int k = threadIdx.x; k < K1; k += 256) {
        int dj = k % 3, t = k / 3;
        int di = t % 3, c = t / 3;
        int yy = py + di - 1, xx = px + dj - 1;
        float v = 0.f;
        if (yy >= 0 && yy < DH && xx >= 0 && xx < DW)
            v = src[((size_t)c * HH + (yy << 1)) * WW + (xx << 1)];
        unsigned short hi = f2bf(v);
        unsigned short lo = f2bf(v - bf2f(hi));
        dst[base + k] = hi;
        dst[base + K1 + k]     = lo_in_seg1 ? lo : hi;
        dst[base + 2 * K1 + k] = lo_in_seg1 ? hi : lo;
    }
}

// ---------------- raw 4x4 stride-2 patches of full-res b, transposed: dst[m2][p] bf16 ----------------
__global__ __launch_bounds__(256) void im2col_rawt_kernel(
    const float* __restrict__ src, unsigned short* __restrict__ dst)
{
    int idx = blockIdx.x * 256 + threadIdx.x;   // K2*LTOT threads, p fastest
    int p = idx & (LTOT - 1);
    int m = idx >> 12;
    int px = p & 63, py = p >> 6;
    int ke = m & 3, kd = (m >> 2) & 3, c = m >> 4;
    int yy = 2 * py - 1 + kd, xx = 2 * px - 1 + ke;
    float v = 0.f;
    if (yy >= 0 && yy < HH && xx >= 0 && xx < WW)
        v = src[((size_t)c * HH + yy) * WW + xx];
    dst[idx] = f2bf(v);
}

// ---------------- per-pixel sum of squares over channels (on downsampled b) ----------------
__global__ void ssq_kernel(const float* __restrict__ b, float* __restrict__ ssq) {
    int p = blockIdx.x * blockDim.x + threadIdx.x;     // 4096
    int px = p & 63, py = p >> 6;
    float s = 0.f;
    for (int c = 0; c < CC; ++c) {
        float v = b[((size_t)c * HH + 2 * py) * WW + 2 * px];
        s += v * v;
    }
    ssq[p] = s;
}

// ---------------- patch inverse norm + mask gate ----------------
__global__ void norm_mm_kernel(const float* __restrict__ ssq, const float* __restrict__ mask,
                               float* __restrict__ inv_norm, float* __restrict__ mmv) {
    int p = blockIdx.x * blockDim.x + threadIdx.x;     // 4096
    int px = p & 63, py = p >> 6;
    float s = 0.f, ms = 0.f;
    for (int di = -1; di <= 1; ++di)
        for (int dj = -1; dj <= 1; ++dj) {
            int y = py + di, x = px + dj;
            if (y >= 0 && y < DH && x >= 0 && x < DW) {
                s += ssq[y * 64 + x];
                ms += mask[(size_t)(2 * y) * WW + 2 * x];
            }
        }
    float n = sqrtf(s);
    if (n < 1e-4f) n = 1e-4f;
    inv_norm[p] = 1.f / n;
    mmv[p] = (ms == 0.f) ? 1.f : 0.f;
}

// ---------------- bf16 MFMA GEMM (m97 structure): A[M][K], B[N][K], C[M][N] fp32 ----------------
// 128x128 tile, BK=32, 4 waves in 2x2, each wave 4x4 MFMA 16x16x32 tiles.
__global__ __launch_bounds__(256) void gemm_mfma(
    const unsigned short* __restrict__ Aop, const unsigned short* __restrict__ Bop,
    float* __restrict__ C, const float* __restrict__ rowscale,
    int M, int N, int K)
{
    __shared__ short As[128 * 32];   // [m][k] rows of 64B
    __shared__ short Bs[128 * 32];
    int tid = threadIdx.x;
    int wave = tid >> 6, lane = tid & 63;
    int wm = (wave >> 1) * 64;
    int wn = (wave & 1) * 64;
    int bm = blockIdx.y * 128, bn = blockIdx.x * 128;

    int rowS = wave * 32;                 // this wave stages rows [rowS, rowS+32)
    int lrow = lane >> 2;                 // 0..15 within 16-row group
    int lcol = (lane & 3) * 8;            // k offset (shorts), 16B chunks

    f32x4 acc[4][4] = {};

    int quad = lane >> 4;                 // k-slab for MFMA fragments
    int r16 = lane & 15;

    for (int k0 = 0; k0 < K; k0 += 32) {
        const unsigned short* ag = Aop + (size_t)(bm + rowS + lrow) * K + k0 + lcol;
        const unsigned short* bg = Bop + (size_t)(bn + rowS + lrow) * K + k0 + lcol;
        GLDS16(ag,            As + rowS * 32);
        GLDS16(ag + 16 * (size_t)K, As + (rowS + 16) * 32);
        GLDS16(bg,            Bs + rowS * 32);
        GLDS16(bg + 16 * (size_t)K, Bs + (rowS + 16) * 32);
        __syncthreads();

        short8 a[4], b[4];
#pragma unroll
        for (int i = 0; i < 4; ++i) {
            a[i] = *(const short8*)&As[(wm + i * 16 + r16) * 32 + quad * 8];
            b[i] = *(const short8*)&Bs[(wn + i * 16 + r16) * 32 + quad * 8];
        }
#pragma unroll
        for (int i = 0; i < 4; ++i)
#pragma unroll
            for (int j = 0; j < 4; ++j)
                acc[i][j] = __builtin_amdgcn_mfma_f32_16x16x32_bf16(a[i], b[j], acc[i][j], 0, 0, 0);
        __syncthreads();
    }

    int col = lane & 15, rq = (lane >> 4) * 4;
#pragma unroll
    for (int i = 0; i < 4; ++i) {
#pragma unroll
        for (int r = 0; r < 4; ++r) {
            int m = bm + wm + i * 16 + rq + r;
            float sc = rowscale ? rowscale[m] : 1.f;
#pragma unroll
            for (int j = 0; j < 4; ++j)
                C[(size_t)m * N + bn + wn + j * 16 + col] = acc[i][j][r] * sc;
        }
    }
}

// ---------------- fuse 1: out[l][p] = sum_d in[l+d][p+d] on flat 4096x4096, zero-pad ----------------
__global__ void fuse1_kernel(const float* __restrict__ A, float* __restrict__ O) {
    int idx = blockIdx.x * blockDim.x + threadIdx.x;   // LTOT*LTOT
    int P = idx & (LTOT - 1);
    int Lr = idx >> 12;
    float s = 0.f;
#pragma unroll
    for (int d = -1; d <= 1; ++d) {
        int r = Lr + d, c = P + d;
        if (r >= 0 && r < LTOT && c >= 0 && c < LTOT)
            s += A[(size_t)r * LTOT + c];
    }
    O[idx] = s;
}

// ---------------- fuse 2: same conv in transposed (bx-major / fx-major) flat layout ----------------
__global__ void fuse2_kernel(const float* __restrict__ A, float* __restrict__ O) {
    int idx = blockIdx.x * blockDim.x + threadIdx.x;   // LTOT*LTOT
    int P = idx & (LTOT - 1);
    int Lr = idx >> 12;
    int by = Lr >> 6, bx = Lr & 63;
    int fy = P >> 6,  fx = P & 63;
    int rbase = bx * 64 + by;
    int cbase = fx * 64 + fy;
    float s = 0.f;
#pragma unroll
    for (int d = -1; d <= 1; ++d) {
        int r = rbase + d, c = cbase + d;
        if (r >= 0 && r < LTOT && c >= 0 && c < LTOT) {
            int L2 = (r & 63) * 64 + (r >> 6);
            int P2 = (c & 63) * 64 + (c >> 6);
            s += A[(size_t)L2 * LTOT + P2];
        }
    }
    O[idx] = s;
}

// ---------------- column softmax over the 4096 patch axis (in place, fp32) ----------------
__global__ __launch_bounds__(256) void softmax_kernel(float* __restrict__ A, const float* __restrict__ mmv) {
    __shared__ float red[4][64];
    int tid = threadIdx.x;
    int lane = tid & 63;
    int col = blockIdx.x * 64 + lane;
    int seg = tid >> 6;
    int l0 = seg * 1024, l1 = l0 + 1024;

    float mx = -3.4e38f;
    for (int l = l0; l < l1; ++l) {
        float v = A[(size_t)l * LTOT + col] * mmv[l] * SCALE_F;
        mx = fmaxf(mx, v);
    }
    red[seg][lane] = mx;
    __syncthreads();
    float gmx = fmaxf(fmaxf(red[0][lane], red[1][lane]),
                      fmaxf(red[2][lane], red[3][lane]));
    __syncthreads();

    float s = 0.f;
    for (int l = l0; l < l1; ++l) {
        float v = A[(size_t)l * LTOT + col] * mmv[l] * SCALE_F;
        s += __expf(v - gmx);
    }
    red[seg][lane] = s;
    __syncthreads();
    float gs = red[0][lane] + red[1][lane] + red[2][lane] + red[3][lane];
    float inv = 1.f / gs;

    for (int l = l0; l < l1; ++l) {
        size_t o = (size_t)l * LTOT + col;
        float v = A[o] * mmv[l] * SCALE_F;
        A[o] = __expf(v - gmx) * inv * mmv[l];
    }
}

// ---------------- transpose + cast: At[q][p] bf16 from A[p][q] fp32, 64x64 LDS tiles ----------------
__global__ __launch_bounds__(256) void transpose_cast_kernel(
    const float* __restrict__ A, unsigned short* __restrict__ At)
{
    __shared__ float tile[64][65];
    int bq = blockIdx.x * 64;   // q (col of A)
    int bp = blockIdx.y * 64;   // p (row of A)
    int tx = threadIdx.x & 63, ty = threadIdx.x >> 6;
    for (int r = ty; r < 64; r += 4)
        tile[r][tx] = A[(size_t)(bp + r) * LTOT + bq + tx];
    __syncthreads();
    for (int r = ty; r < 64; r += 4)
        At[(size_t)(bq + r) * LTOT + bp + tx] = f2bf(tile[tx][r]);
}

// ---------------- overlap-add of weighted 4x4 patches (stride 2), /4 ----------------
__global__ void output_kernel(const float* __restrict__ C2, float* __restrict__ out) {
    int idx = blockIdx.x * blockDim.x + threadIdx.x;   // CC*HH*WW
    int x = idx & 127;
    int y = (idx >> 7) & 127;
    int c = idx >> 14;
    int oylo = max(0, (y - 1) >> 1), oyhi = min(63, (y + 1) >> 1);
    int oxlo = max(0, (x - 1) >> 1), oxhi = min(63, (x + 1) >> 1);
    float s = 0.f;
    for (int oy = oylo; oy <= oyhi; ++oy)
        for (int ox = oxlo; ox <= oxhi; ++ox) {
            int kd = y - 2 * oy + 1;
            int ke = x - 2 * ox + 1;
            s += C2[(size_t)(oy * 64 + ox) * K2 + c * 16 + kd * 4 + ke];
        }
    out[idx] = s * 0.25f;
}

extern "C" void kernel_launch(void* const* d_in, const int* in_sizes, int n_in,
                              void* d_out, int out_size, void* d_ws, size_t ws_size,
                              hipStream_t stream) {
    (void)in_sizes; (void)n_in; (void)out_size; (void)ws_size;
    const float* f    = (const float*)d_in[0];
    const float* b    = (const float*)d_in[1];
    const float* mask = (const float*)d_in[2];
    float* out = (float*)d_out;

    char* ws = (char*)d_ws;
    size_t off = 0;
    auto alloc = [&](size_t bytes) -> void* {
        void* p = (void*)(ws + off);
        off += (bytes + 255) & ~(size_t)255;
        return p;
    };
    float* A    = (float*)alloc((size_t)LTOT * LTOT * 4);          // 64 MB: scores -> softmax -> C2
    float* Atmp = (float*)alloc((size_t)LTOT * LTOT * 4);          // 64 MB: fuse ping-pong -> At (bf16)
    unsigned short* A1 = (unsigned short*)alloc((size_t)LTOT * K1S * 2);  // 28.3 MB b-patch split
    unsigned short* B1 = (unsigned short*)alloc((size_t)LTOT * K1S * 2);  // 28.3 MB f-patch split
    float* ssq  = (float*)alloc(LTOT * 4);
    float* invn = (float*)alloc(LTOT * 4);
    float* mmv  = (float*)alloc(LTOT * 4);

    unsigned short* Wrawt = A1;                 // [K2][LTOT] bf16, reuses A1 after GEMM1
    unsigned short* At    = (unsigned short*)Atmp;  // [q][p] bf16, reuses Atmp after fuse2
    float* C2 = A;                               // [q][K2] fp32, reuses A after transpose

    for (int bi = 0; bi < 2; ++bi) {
        const float* fb = f + (size_t)bi * CC * HH * WW;
        const float* bb = b + (size_t)bi * CC * HH * WW;

        im2col_split_kernel<<<LTOT, 256, 0, stream>>>(bb, A1, 1);   // [hi, lo, hi]
        im2col_split_kernel<<<LTOT, 256, 0, stream>>>(fb, B1, 0);   // [hi, hi, lo]
        ssq_kernel<<<LTOT / 256, 256, 0, stream>>>(bb, ssq);
        norm_mm_kernel<<<LTOT / 256, 256, 0, stream>>>(ssq, mask, invn, mmv);

        // A[p][q] = invn[p] * sum_k' A1[p][k'] * B1[q][k']   (split-concat fp32-accurate)
        gemm_mfma<<<dim3(LTOT / 128, LTOT / 128), 256, 0, stream>>>(
            A1, B1, A, invn, LTOT, LTOT, K1S);

        fuse1_kernel<<<(size_t)LTOT * LTOT / 256, 256, 0, stream>>>(A, Atmp);
        fuse2_kernel<<<(size_t)LTOT * LTOT / 256, 256, 0, stream>>>(Atmp, A);

        softmax_kernel<<<LTOT / 64, 256, 0, stream>>>(A, mmv);

        transpose_cast_kernel<<<dim3(64, 64), 256, 0, stream>>>(A, At);

        im2col_rawt_kernel<<<(size_t)K2 * LTOT / 256, 256, 0, stream>>>(bb, Wrawt);

        // C2[q][m2] = sum_p At[q][p] * Wrawt[m2][p]
        gemm_mfma<<<dim3(K2 / 128, LTOT / 128), 256, 0, stream>>>(
            At, Wrawt, C2, nullptr, LTOT, K2, LTOT);

        output_kernel<<<CC * HH * WW / 256, 256, 0, stream>>>(C2, out + (size_t)bi * CC * HH * WW);
    }
}

// Round 3
// 1004.090 us; speedup vs baseline: 3.5490x; 1.5873x over previous
//
#include <hip/hip_runtime.h>

#define CC 128
#define HH 128
#define WW 128
#define DH 64
#define DW 64
#define LTOT 4096          // DH*DW patches / fg positions
#define K1 1152            // CC*3*3
#define K1S 3456           // 3*K1 split-concat K for GEMM1
#define K2 2048            // CC*4*4
#define SCALE_F 10.0f

typedef __attribute__((ext_vector_type(8))) short short8;
typedef __attribute__((ext_vector_type(4))) float f32x4;

// ---- bf16 helpers (RNE) ----
__device__ __forceinline__ unsigned short f2bf(float x) {
    union { float f; unsigned u; } v; v.f = x;
    unsigned r = v.u + 0x7fffu + ((v.u >> 16) & 1u);
    return (unsigned short)(r >> 16);
}
__device__ __forceinline__ float bf2f(unsigned short b) {
    union { unsigned u; float f; } v; v.u = ((unsigned)b) << 16;
    return v.f;
}

#define GLDS16(g, l) __builtin_amdgcn_global_load_lds( \
    (const __attribute__((address_space(1))) void*)(g), \
    (__attribute__((address_space(3))) void*)(l), 16, 0, 0)

// ---------------- im2col + fp32->bf16 split, M-major [p][3456] ----------------
// segments: lo_in_seg1 ? [hi, lo, hi] : [hi, hi, lo]
__global__ __launch_bounds__(256) void im2col_split_kernel(
    const float* __restrict__ src, unsigned short* __restrict__ dst, int lo_in_seg1)
{
    int p = blockIdx.x;                 // 4096 blocks
    int px = p & 63, py = p >> 6;
    size_t base = (size_t)p * K1S;
    for (int k = threadIdx.x; k < K1; k += 256) {
        int dj = k % 3, t = k / 3;
        int di = t % 3, c = t / 3;
        int yy = py + di - 1, xx = px + dj - 1;
        float v = 0.f;
        if (yy >= 0 && yy < DH && xx >= 0 && xx < DW)
            v = src[((size_t)c * HH + (yy << 1)) * WW + (xx << 1)];
        unsigned short hi = f2bf(v);
        unsigned short lo = f2bf(v - bf2f(hi));
        dst[base + k] = hi;
        dst[base + K1 + k]     = lo_in_seg1 ? lo : hi;
        dst[base + 2 * K1 + k] = lo_in_seg1 ? hi : lo;
    }
}

// ---------------- raw 4x4 stride-2 patches of full-res b, transposed: dst[m2][p] bf16 ----------------
__global__ __launch_bounds__(256) void im2col_rawt_kernel(
    const float* __restrict__ src, unsigned short* __restrict__ dst)
{
    int idx = blockIdx.x * 256 + threadIdx.x;   // K2*LTOT threads, p fastest
    int p = idx & (LTOT - 1);
    int m = idx >> 12;
    int px = p & 63, py = p >> 6;
    int ke = m & 3, kd = (m >> 2) & 3, c = m >> 4;
    int yy = 2 * py - 1 + kd, xx = 2 * px - 1 + ke;
    float v = 0.f;
    if (yy >= 0 && yy < HH && xx >= 0 && xx < WW)
        v = src[((size_t)c * HH + yy) * WW + xx];
    dst[idx] = f2bf(v);
}

// ---------------- per-pixel sum of squares over channels (on downsampled b) ----------------
__global__ void ssq_kernel(const float* __restrict__ b, float* __restrict__ ssq) {
    int p = blockIdx.x * blockDim.x + threadIdx.x;     // 4096
    int px = p & 63, py = p >> 6;
    float s = 0.f;
    for (int c = 0; c < CC; ++c) {
        float v = b[((size_t)c * HH + 2 * py) * WW + 2 * px];
        s += v * v;
    }
    ssq[p] = s;
}

// ---------------- patch inverse norm + mask gate ----------------
__global__ void norm_mm_kernel(const float* __restrict__ ssq, const float* __restrict__ mask,
                               float* __restrict__ inv_norm, float* __restrict__ mmv) {
    int p = blockIdx.x * blockDim.x + threadIdx.x;     // 4096
    int px = p & 63, py = p >> 6;
    float s = 0.f, ms = 0.f;
    for (int di = -1; di <= 1; ++di)
        for (int dj = -1; dj <= 1; ++dj) {
            int y = py + di, x = px + dj;
            if (y >= 0 && y < DH && x >= 0 && x < DW) {
                s += ssq[y * 64 + x];
                ms += mask[(size_t)(2 * y) * WW + 2 * x];
            }
        }
    float n = sqrtf(s);
    if (n < 1e-4f) n = 1e-4f;
    inv_norm[p] = 1.f / n;
    mmv[p] = (ms == 0.f) ? 1.f : 0.f;
}

// ---------------- bf16 MFMA GEMM (m97 structure): A[M][K], B[N][K], C[M][N] fp32 ----------------
// 128x128 tile, BK=32, 4 waves in 2x2, each wave 4x4 MFMA 16x16x32 tiles.
// colscale (optional) applies per output column n.
__global__ __launch_bounds__(256) void gemm_mfma(
    const unsigned short* __restrict__ Aop, const unsigned short* __restrict__ Bop,
    float* __restrict__ C, const float* __restrict__ colscale,
    int M, int N, int K)
{
    __shared__ short As[128 * 32];   // [m][k] rows of 64B
    __shared__ short Bs[128 * 32];
    int tid = threadIdx.x;
    int wave = tid >> 6, lane = tid & 63;
    int wm = (wave >> 1) * 64;
    int wn = (wave & 1) * 64;
    int bm = blockIdx.y * 128, bn = blockIdx.x * 128;

    int rowS = wave * 32;                 // this wave stages rows [rowS, rowS+32)
    int lrow = lane >> 2;                 // 0..15 within 16-row group
    int lcol = (lane & 3) * 8;            // k offset (shorts), 16B chunks

    f32x4 acc[4][4] = {};

    int quad = lane >> 4;                 // k-slab for MFMA fragments
    int r16 = lane & 15;

    for (int k0 = 0; k0 < K; k0 += 32) {
        const unsigned short* ag = Aop + (size_t)(bm + rowS + lrow) * K + k0 + lcol;
        const unsigned short* bg = Bop + (size_t)(bn + rowS + lrow) * K + k0 + lcol;
        GLDS16(ag,            As + rowS * 32);
        GLDS16(ag + 16 * (size_t)K, As + (rowS + 16) * 32);
        GLDS16(bg,            Bs + rowS * 32);
        GLDS16(bg + 16 * (size_t)K, Bs + (rowS + 16) * 32);
        __syncthreads();

        short8 a[4], b[4];
#pragma unroll
        for (int i = 0; i < 4; ++i) {
            a[i] = *(const short8*)&As[(wm + i * 16 + r16) * 32 + quad * 8];
            b[i] = *(const short8*)&Bs[(wn + i * 16 + r16) * 32 + quad * 8];
        }
#pragma unroll
        for (int i = 0; i < 4; ++i)
#pragma unroll
            for (int j = 0; j < 4; ++j)
                acc[i][j] = __builtin_amdgcn_mfma_f32_16x16x32_bf16(a[i], b[j], acc[i][j], 0, 0, 0);
        __syncthreads();
    }

    int col = lane & 15, rq = (lane >> 4) * 4;
    float csc[4];
#pragma unroll
    for (int j = 0; j < 4; ++j)
        csc[j] = colscale ? colscale[bn + wn + j * 16 + col] : 1.f;
#pragma unroll
    for (int i = 0; i < 4; ++i) {
#pragma unroll
        for (int r = 0; r < 4; ++r) {
            int m = bm + wm + i * 16 + rq + r;
#pragma unroll
            for (int j = 0; j < 4; ++j)
                C[(size_t)m * N + bn + wn + j * 16 + col] = acc[i][j][r] * csc[j];
        }
    }
}

// ---------------- fuse 1: out[r][c] = sum_d in[r+d][c+d] on flat 4096x4096, zero-pad ----------------
// (diagonal conv is transpose-symmetric; rows=q, cols=p in the S layout)
__global__ void fuse1_kernel(const float* __restrict__ A, float* __restrict__ O) {
    int idx = blockIdx.x * blockDim.x + threadIdx.x;   // LTOT*LTOT
    int P = idx & (LTOT - 1);
    int Lr = idx >> 12;
    float s = 0.f;
#pragma unroll
    for (int d = -1; d <= 1; ++d) {
        int r = Lr + d, c = P + d;
        if (r >= 0 && r < LTOT && c >= 0 && c < LTOT)
            s += A[(size_t)r * LTOT + c];
    }
    O[idx] = s;
}

// ---------------- fuse 2: same conv in swap-permuted flat layout (also transpose-symmetric) ----------------
__global__ void fuse2_kernel(const float* __restrict__ A, float* __restrict__ O) {
    int idx = blockIdx.x * blockDim.x + threadIdx.x;   // LTOT*LTOT
    int P = idx & (LTOT - 1);
    int Lr = idx >> 12;
    int rbase = (Lr & 63) * 64 + (Lr >> 6);
    int cbase = (P & 63) * 64 + (P >> 6);
    float s = 0.f;
#pragma unroll
    for (int d = -1; d <= 1; ++d) {
        int r = rbase + d, c = cbase + d;
        if (r >= 0 && r < LTOT && c >= 0 && c < LTOT) {
            int L2 = (r & 63) * 64 + (r >> 6);
            int P2 = (c & 63) * 64 + (c >> 6);
            s += A[(size_t)L2 * LTOT + P2];
        }
    }
    O[idx] = s;
}

// ---------------- row softmax over p (contiguous), write bf16 [q][p] directly ----------------
// logits = S[q][p] * mm[p] * 10 ; out = softmax_row(logits) * mm[p]
__global__ __launch_bounds__(256) void softmax_row_kernel(
    const float* __restrict__ S, const float* __restrict__ mmv,
    unsigned short* __restrict__ S16)
{
    __shared__ float redmax[4];
    __shared__ float redsum[4];
    int q = blockIdx.x;
    int t = threadIdx.x;
    int lane = t & 63, wid = t >> 6;
    const float4* row4 = (const float4*)(S + (size_t)q * LTOT);
    const float4* mm4 = (const float4*)mmv;

    float v[16], m[16];
#pragma unroll
    for (int i = 0; i < 4; ++i) {
        float4 x = row4[t + 256 * i];
        float4 mmx = mm4[t + 256 * i];
        v[4*i+0] = x.x * mmx.x * SCALE_F;  m[4*i+0] = mmx.x;
        v[4*i+1] = x.y * mmx.y * SCALE_F;  m[4*i+1] = mmx.y;
        v[4*i+2] = x.z * mmx.z * SCALE_F;  m[4*i+2] = mmx.z;
        v[4*i+3] = x.w * mmx.w * SCALE_F;  m[4*i+3] = mmx.w;
    }

    float mx = v[0];
#pragma unroll
    for (int i = 1; i < 16; ++i) mx = fmaxf(mx, v[i]);
#pragma unroll
    for (int o = 32; o; o >>= 1) mx = fmaxf(mx, __shfl_xor(mx, o));
    if (lane == 0) redmax[wid] = mx;
    __syncthreads();
    float gmx = fmaxf(fmaxf(redmax[0], redmax[1]), fmaxf(redmax[2], redmax[3]));

    float s = 0.f;
#pragma unroll
    for (int i = 0; i < 16; ++i) {
        v[i] = __expf(v[i] - gmx);
        s += v[i];
    }
#pragma unroll
    for (int o = 32; o; o >>= 1) s += __shfl_xor(s, o);
    if (lane == 0) redsum[wid] = s;
    __syncthreads();
    float inv = 1.f / (redsum[0] + redsum[1] + redsum[2] + redsum[3]);

    unsigned short* orow = S16 + (size_t)q * LTOT;
#pragma unroll
    for (int i = 0; i < 4; ++i) {
        ushort4 u;
        u.x = f2bf(v[4*i+0] * inv * m[4*i+0]);
        u.y = f2bf(v[4*i+1] * inv * m[4*i+1]);
        u.z = f2bf(v[4*i+2] * inv * m[4*i+2]);
        u.w = f2bf(v[4*i+3] * inv * m[4*i+3]);
        *(ushort4*)(orow + (t + 256 * i) * 4) = u;
    }
}

// ---------------- overlap-add of weighted 4x4 patches (stride 2), /4 ----------------
__global__ void output_kernel(const float* __restrict__ C2, float* __restrict__ out) {
    int idx = blockIdx.x * blockDim.x + threadIdx.x;   // CC*HH*WW
    int x = idx & 127;
    int y = (idx >> 7) & 127;
    int c = idx >> 14;
    int oylo = max(0, (y - 1) >> 1), oyhi = min(63, (y + 1) >> 1);
    int oxlo = max(0, (x - 1) >> 1), oxhi = min(63, (x + 1) >> 1);
    float s = 0.f;
    for (int oy = oylo; oy <= oyhi; ++oy)
        for (int ox = oxlo; ox <= oxhi; ++ox) {
            int kd = y - 2 * oy + 1;
            int ke = x - 2 * ox + 1;
            s += C2[(size_t)(oy * 64 + ox) * K2 + c * 16 + kd * 4 + ke];
        }
    out[idx] = s * 0.25f;
}

extern "C" void kernel_launch(void* const* d_in, const int* in_sizes, int n_in,
                              void* d_out, int out_size, void* d_ws, size_t ws_size,
                              hipStream_t stream) {
    (void)in_sizes; (void)n_in; (void)out_size; (void)ws_size;
    const float* f    = (const float*)d_in[0];
    const float* b    = (const float*)d_in[1];
    const float* mask = (const float*)d_in[2];
    float* out = (float*)d_out;

    char* ws = (char*)d_ws;
    size_t off = 0;
    auto alloc = [&](size_t bytes) -> void* {
        void* p = (void*)(ws + off);
        off += (bytes + 255) & ~(size_t)255;
        return p;
    };
    float* S    = (float*)alloc((size_t)LTOT * LTOT * 4);          // 64 MB: scores [q][p] -> C2
    float* Stmp = (float*)alloc((size_t)LTOT * LTOT * 4);          // 64 MB: fuse ping-pong -> S16 (bf16)
    unsigned short* Wsp = (unsigned short*)alloc((size_t)LTOT * K1S * 2);  // 28.3 MB b-patch split [p][k']
    unsigned short* Fsp = (unsigned short*)alloc((size_t)LTOT * K1S * 2);  // 28.3 MB f-patch split [q][k']
    float* ssq  = (float*)alloc(LTOT * 4);
    float* invn = (float*)alloc(LTOT * 4);
    float* mmv  = (float*)alloc(LTOT * 4);

    unsigned short* Wrawt = Wsp;                    // [K2][LTOT] bf16, reuses Wsp after GEMM1
    unsigned short* S16   = (unsigned short*)Stmp;  // [q][p] bf16, reuses Stmp after fuse2
    float* C2 = S;                                   // [q][K2] fp32, reuses S after softmax

    for (int bi = 0; bi < 2; ++bi) {
        const float* fb = f + (size_t)bi * CC * HH * WW;
        const float* bb = b + (size_t)bi * CC * HH * WW;

        im2col_split_kernel<<<LTOT, 256, 0, stream>>>(bb, Wsp, 1);   // [hi, lo, hi]
        im2col_split_kernel<<<LTOT, 256, 0, stream>>>(fb, Fsp, 0);   // [hi, hi, lo]
        ssq_kernel<<<LTOT / 256, 256, 0, stream>>>(bb, ssq);
        norm_mm_kernel<<<LTOT / 256, 256, 0, stream>>>(ssq, mask, invn, mmv);

        // S[q][p] = invn[p] * sum_k' Fsp[q][k'] * Wsp[p][k']   (split-concat fp32-accurate)
        gemm_mfma<<<dim3(LTOT / 128, LTOT / 128), 256, 0, stream>>>(
            Fsp, Wsp, S, invn, LTOT, LTOT, K1S);

        fuse1_kernel<<<(size_t)LTOT * LTOT / 256, 256, 0, stream>>>(S, Stmp);
        fuse2_kernel<<<(size_t)LTOT * LTOT / 256, 256, 0, stream>>>(Stmp, S);

        im2col_rawt_kernel<<<(size_t)K2 * LTOT / 256, 256, 0, stream>>>(bb, Wrawt);

        softmax_row_kernel<<<LTOT, 256, 0, stream>>>(S, mmv, S16);

        // C2[q][m2] = sum_p S16[q][p] * Wrawt[m2][p]
        gemm_mfma<<<dim3(K2 / 128, LTOT / 128), 256, 0, stream>>>(
            S16, Wrawt, C2, nullptr, LTOT, K2, LTOT);

        output_kernel<<<CC * HH * WW / 256, 256, 0, stream>>>(C2, out + (size_t)bi * CC * HH * WW);
    }
}

// Round 4
// 989.619 us; speedup vs baseline: 3.6009x; 1.0146x over previous
//
#include <hip/hip_runtime.h>

#define CC 128
#define HH 128
#define WW 128
#define DH 64
#define DW 64
#define LTOT 4096          // DH*DW patches / fg positions
#define K1 1152            // CC*3*3
#define K1S 3456           // 3*K1 split-concat K for GEMM1
#define K2 2048            // CC*4*4
#define SCALE_F 10.0f

typedef __attribute__((ext_vector_type(8))) short short8;
typedef __attribute__((ext_vector_type(4))) float f32x4;

// ---- bf16 helpers (RNE) ----
__device__ __forceinline__ unsigned short f2bf(float x) {
    union { float f; unsigned u; } v; v.f = x;
    unsigned r = v.u + 0x7fffu + ((v.u >> 16) & 1u);
    return (unsigned short)(r >> 16);
}
__device__ __forceinline__ float bf2f(unsigned short b) {
    union { unsigned u; float f; } v; v.u = ((unsigned)b) << 16;
    return v.f;
}

#define GLDS16(g, l) __builtin_amdgcn_global_load_lds( \
    (const __attribute__((address_space(1))) void*)(g), \
    (__attribute__((address_space(3))) void*)(l), 16, 0, 0)

// ---------------- im2col + fp32->bf16 split, M-major [p][3456] ----------------
// segments: lo_in_seg1 ? [hi, lo, hi] : [hi, hi, lo]
__global__ __launch_bounds__(256) void im2col_split_kernel(
    const float* __restrict__ src, unsigned short* __restrict__ dst, int lo_in_seg1)
{
    int p = blockIdx.x;                 // 4096 blocks
    int px = p & 63, py = p >> 6;
    size_t base = (size_t)p * K1S;
    for (int k = threadIdx.x; k < K1; k += 256) {
        int dj = k % 3, t = k / 3;
        int di = t % 3, c = t / 3;
        int yy = py + di - 1, xx = px + dj - 1;
        float v = 0.f;
        if (yy >= 0 && yy < DH && xx >= 0 && xx < DW)
            v = src[((size_t)c * HH + (yy << 1)) * WW + (xx << 1)];
        unsigned short hi = f2bf(v);
        unsigned short lo = f2bf(v - bf2f(hi));
        dst[base + k] = hi;
        dst[base + K1 + k]     = lo_in_seg1 ? lo : hi;
        dst[base + 2 * K1 + k] = lo_in_seg1 ? hi : lo;
    }
}

// ---------------- raw 4x4 stride-2 patches of full-res b, transposed: dst[m2][p] bf16 ----------------
__global__ __launch_bounds__(256) void im2col_rawt_kernel(
    const float* __restrict__ src, unsigned short* __restrict__ dst)
{
    int idx = blockIdx.x * 256 + threadIdx.x;   // K2*LTOT threads, p fastest
    int p = idx & (LTOT - 1);
    int m = idx >> 12;
    int px = p & 63, py = p >> 6;
    int ke = m & 3, kd = (m >> 2) & 3, c = m >> 4;
    int yy = 2 * py - 1 + kd, xx = 2 * px - 1 + ke;
    float v = 0.f;
    if (yy >= 0 && yy < HH && xx >= 0 && xx < WW)
        v = src[((size_t)c * HH + yy) * WW + xx];
    dst[idx] = f2bf(v);
}

// ---------------- per-pixel sum of squares over channels (on downsampled b) ----------------
__global__ void ssq_kernel(const float* __restrict__ b, float* __restrict__ ssq) {
    int p = blockIdx.x * blockDim.x + threadIdx.x;     // 4096
    int px = p & 63, py = p >> 6;
    float s = 0.f;
    for (int c = 0; c < CC; ++c) {
        float v = b[((size_t)c * HH + 2 * py) * WW + 2 * px];
        s += v * v;
    }
    ssq[p] = s;
}

// ---------------- patch inverse norm + mask gate ----------------
__global__ void norm_mm_kernel(const float* __restrict__ ssq, const float* __restrict__ mask,
                               float* __restrict__ inv_norm, float* __restrict__ mmv) {
    int p = blockIdx.x * blockDim.x + threadIdx.x;     // 4096
    int px = p & 63, py = p >> 6;
    float s = 0.f, ms = 0.f;
    for (int di = -1; di <= 1; ++di)
        for (int dj = -1; dj <= 1; ++dj) {
            int y = py + di, x = px + dj;
            if (y >= 0 && y < DH && x >= 0 && x < DW) {
                s += ssq[y * 64 + x];
                ms += mask[(size_t)(2 * y) * WW + 2 * x];
            }
        }
    float n = sqrtf(s);
    if (n < 1e-4f) n = 1e-4f;
    inv_norm[p] = 1.f / n;
    mmv[p] = (ms == 0.f) ? 1.f : 0.f;
}

// ---------------- bf16 MFMA GEMM (m97 structure + XOR bank swizzle) ----------------
// A[M][K], B[N][K], C[M][N] fp32. 128x128 tile, BK=32, 4 waves 2x2, 4x4 MFMA 16x16x32.
// LDS slot s (16B chunks) of row m holds global k-chunk s ^ ((m>>1)&3):
// realized on the global side (GLDS scatter is fixed lane*16), undone at fragment read.
// colscale (optional) applies per output column n.
__global__ __launch_bounds__(256) void gemm_mfma(
    const unsigned short* __restrict__ Aop, const unsigned short* __restrict__ Bop,
    float* __restrict__ C, const float* __restrict__ colscale,
    int M, int N, int K)
{
    __shared__ short As[128 * 32];   // [m][k-chunk swizzled] rows of 64B
    __shared__ short Bs[128 * 32];
    int tid = threadIdx.x;
    int wave = tid >> 6, lane = tid & 63;
    int wm = (wave >> 1) * 64;
    int wn = (wave & 1) * 64;
    int bm = blockIdx.y * 128, bn = blockIdx.x * 128;

    int rowS = wave * 32;                 // this wave stages rows [rowS, rowS+32)
    int lrow = lane >> 2;                 // 0..15 within 16-row group
    // swizzled global k-chunk for this lane's fixed LDS slot (lane&3):
    int lcol = (((lane & 3) ^ ((lrow >> 1) & 3)) * 8);

    f32x4 acc[4][4] = {};

    int quad = lane >> 4;                 // k-slab for MFMA fragments
    int r16 = lane & 15;
    int slotA = (quad ^ ((r16 >> 1) & 3)) * 8;   // un-swizzle at read

    for (int k0 = 0; k0 < K; k0 += 32) {
        const unsigned short* ag = Aop + (size_t)(bm + rowS + lrow) * K + k0 + lcol;
        const unsigned short* bg = Bop + (size_t)(bn + rowS + lrow) * K + k0 + lcol;
        GLDS16(ag,                  As + rowS * 32);
        GLDS16(ag + 16 * (size_t)K, As + (rowS + 16) * 32);
        GLDS16(bg,                  Bs + rowS * 32);
        GLDS16(bg + 16 * (size_t)K, Bs + (rowS + 16) * 32);
        __syncthreads();

        short8 a[4], b[4];
#pragma unroll
        for (int i = 0; i < 4; ++i) {
            a[i] = *(const short8*)&As[(wm + i * 16 + r16) * 32 + slotA];
            b[i] = *(const short8*)&Bs[(wn + i * 16 + r16) * 32 + slotA];
        }
#pragma unroll
        for (int i = 0; i < 4; ++i)
#pragma unroll
            for (int j = 0; j < 4; ++j)
                acc[i][j] = __builtin_amdgcn_mfma_f32_16x16x32_bf16(a[i], b[j], acc[i][j], 0, 0, 0);
        __syncthreads();
    }

    int col = lane & 15, rq = (lane >> 4) * 4;
    float csc[4];
#pragma unroll
    for (int j = 0; j < 4; ++j)
        csc[j] = colscale ? colscale[bn + wn + j * 16 + col] : 1.f;
#pragma unroll
    for (int i = 0; i < 4; ++i) {
#pragma unroll
        for (int r = 0; r < 4; ++r) {
            int m = bm + wm + i * 16 + rq + r;
#pragma unroll
            for (int j = 0; j < 4; ++j)
                C[(size_t)m * N + bn + wn + j * 16 + col] = acc[i][j][r] * csc[j];
        }
    }
}

// ---------------- fuse 1: out[r][c] = sum_d in[r+d][c+d] on flat 4096x4096, zero-pad ----------------
__global__ void fuse1_kernel(const float* __restrict__ A, float* __restrict__ O) {
    int idx = blockIdx.x * blockDim.x + threadIdx.x;   // LTOT*LTOT
    int P = idx & (LTOT - 1);
    int Lr = idx >> 12;
    float s = 0.f;
#pragma unroll
    for (int d = -1; d <= 1; ++d) {
        int r = Lr + d, c = P + d;
        if (r >= 0 && r < LTOT && c >= 0 && c < LTOT)
            s += A[(size_t)r * LTOT + c];
    }
    O[idx] = s;
}

// ---------------- fuse 2: same conv in swap-permuted flat layout (transpose-symmetric) ----------------
__global__ void fuse2_kernel(const float* __restrict__ A, float* __restrict__ O) {
    int idx = blockIdx.x * blockDim.x + threadIdx.x;   // LTOT*LTOT
    int P = idx & (LTOT - 1);
    int Lr = idx >> 12;
    int rbase = (Lr & 63) * 64 + (Lr >> 6);
    int cbase = (P & 63) * 64 + (P >> 6);
    float s = 0.f;
#pragma unroll
    for (int d = -1; d <= 1; ++d) {
        int r = rbase + d, c = cbase + d;
        if (r >= 0 && r < LTOT && c >= 0 && c < LTOT) {
            int L2 = (r & 63) * 64 + (r >> 6);
            int P2 = (c & 63) * 64 + (c >> 6);
            s += A[(size_t)L2 * LTOT + P2];
        }
    }
    O[idx] = s;
}

// ---------------- row softmax over p (contiguous), write bf16 [q][p] directly ----------------
__global__ __launch_bounds__(256) void softmax_row_kernel(
    const float* __restrict__ S, const float* __restrict__ mmv,
    unsigned short* __restrict__ S16)
{
    __shared__ float redmax[4];
    __shared__ float redsum[4];
    int q = blockIdx.x;
    int t = threadIdx.x;
    int lane = t & 63, wid = t >> 6;
    const float4* row4 = (const float4*)(S + (size_t)q * LTOT);
    const float4* mm4 = (const float4*)mmv;

    float v[16], m[16];
#pragma unroll
    for (int i = 0; i < 4; ++i) {
        float4 x = row4[t + 256 * i];
        float4 mmx = mm4[t + 256 * i];
        v[4*i+0] = x.x * mmx.x * SCALE_F;  m[4*i+0] = mmx.x;
        v[4*i+1] = x.y * mmx.y * SCALE_F;  m[4*i+1] = mmx.y;
        v[4*i+2] = x.z * mmx.z * SCALE_F;  m[4*i+2] = mmx.z;
        v[4*i+3] = x.w * mmx.w * SCALE_F;  m[4*i+3] = mmx.w;
    }

    float mx = v[0];
#pragma unroll
    for (int i = 1; i < 16; ++i) mx = fmaxf(mx, v[i]);
#pragma unroll
    for (int o = 32; o; o >>= 1) mx = fmaxf(mx, __shfl_xor(mx, o));
    if (lane == 0) redmax[wid] = mx;
    __syncthreads();
    float gmx = fmaxf(fmaxf(redmax[0], redmax[1]), fmaxf(redmax[2], redmax[3]));

    float s = 0.f;
#pragma unroll
    for (int i = 0; i < 16; ++i) {
        v[i] = __expf(v[i] - gmx);
        s += v[i];
    }
#pragma unroll
    for (int o = 32; o; o >>= 1) s += __shfl_xor(s, o);
    if (lane == 0) redsum[wid] = s;
    __syncthreads();
    float inv = 1.f / (redsum[0] + redsum[1] + redsum[2] + redsum[3]);

    unsigned short* orow = S16 + (size_t)q * LTOT;
#pragma unroll
    for (int i = 0; i < 4; ++i) {
        ushort4 u;
        u.x = f2bf(v[4*i+0] * inv * m[4*i+0]);
        u.y = f2bf(v[4*i+1] * inv * m[4*i+1]);
        u.z = f2bf(v[4*i+2] * inv * m[4*i+2]);
        u.w = f2bf(v[4*i+3] * inv * m[4*i+3]);
        *(ushort4*)(orow + (t + 256 * i) * 4) = u;
    }
}

// ---------------- overlap-add of weighted 4x4 patches (stride 2), /4 ----------------
__global__ void output_kernel(const float* __restrict__ C2, float* __restrict__ out) {
    int idx = blockIdx.x * blockDim.x + threadIdx.x;   // CC*HH*WW
    int x = idx & 127;
    int y = (idx >> 7) & 127;
    int c = idx >> 14;
    int oylo = max(0, (y - 1) >> 1), oyhi = min(63, (y + 1) >> 1);
    int oxlo = max(0, (x - 1) >> 1), oxhi = min(63, (x + 1) >> 1);
    float s = 0.f;
    for (int oy = oylo; oy <= oyhi; ++oy)
        for (int ox = oxlo; ox <= oxhi; ++ox) {
            int kd = y - 2 * oy + 1;
            int ke = x - 2 * ox + 1;
            s += C2[(size_t)(oy * 64 + ox) * K2 + c * 16 + kd * 4 + ke];
        }
    out[idx] = s * 0.25f;
}

extern "C" void kernel_launch(void* const* d_in, const int* in_sizes, int n_in,
                              void* d_out, int out_size, void* d_ws, size_t ws_size,
                              hipStream_t stream) {
    (void)in_sizes; (void)n_in; (void)out_size; (void)ws_size;
    const float* f    = (const float*)d_in[0];
    const float* b    = (const float*)d_in[1];
    const float* mask = (const float*)d_in[2];
    float* out = (float*)d_out;

    char* ws = (char*)d_ws;
    size_t off = 0;
    auto alloc = [&](size_t bytes) -> void* {
        void* p = (void*)(ws + off);
        off += (bytes + 255) & ~(size_t)255;
        return p;
    };
    float* S    = (float*)alloc((size_t)LTOT * LTOT * 4);          // 64 MB: scores [q][p] -> C2
    float* Stmp = (float*)alloc((size_t)LTOT * LTOT * 4);          // 64 MB: fuse ping-pong -> S16 (bf16)
    unsigned short* Wsp = (unsigned short*)alloc((size_t)LTOT * K1S * 2);  // 28.3 MB b-patch split [p][k']
    unsigned short* Fsp = (unsigned short*)alloc((size_t)LTOT * K1S * 2);  // 28.3 MB f-patch split [q][k']
    float* ssq  = (float*)alloc(LTOT * 4);
    float* invn = (float*)alloc(LTOT * 4);
    float* mmv  = (float*)alloc(LTOT * 4);

    unsigned short* Wrawt = Wsp;                    // [K2][LTOT] bf16, reuses Wsp after GEMM1
    unsigned short* S16   = (unsigned short*)Stmp;  // [q][p] bf16, reuses Stmp after fuse2
    float* C2 = S;                                   // [q][K2] fp32, reuses S after softmax

    for (int bi = 0; bi < 2; ++bi) {
        const float* fb = f + (size_t)bi * CC * HH * WW;
        const float* bb = b + (size_t)bi * CC * HH * WW;

        im2col_split_kernel<<<LTOT, 256, 0, stream>>>(bb, Wsp, 1);   // [hi, lo, hi]
        im2col_split_kernel<<<LTOT, 256, 0, stream>>>(fb, Fsp, 0);   // [hi, hi, lo]
        ssq_kernel<<<LTOT / 256, 256, 0, stream>>>(bb, ssq);
        norm_mm_kernel<<<LTOT / 256, 256, 0, stream>>>(ssq, mask, invn, mmv);

        // S[q][p] = invn[p] * sum_k' Fsp[q][k'] * Wsp[p][k']   (split-concat fp32-accurate)
        gemm_mfma<<<dim3(LTOT / 128, LTOT / 128), 256, 0, stream>>>(
            Fsp, Wsp, S, invn, LTOT, LTOT, K1S);

        fuse1_kernel<<<(size_t)LTOT * LTOT / 256, 256, 0, stream>>>(S, Stmp);
        fuse2_kernel<<<(size_t)LTOT * LTOT / 256, 256, 0, stream>>>(Stmp, S);

        im2col_rawt_kernel<<<(size_t)K2 * LTOT / 256, 256, 0, stream>>>(bb, Wrawt);

        softmax_row_kernel<<<LTOT, 256, 0, stream>>>(S, mmv, S16);

        // C2[q][m2] = sum_p S16[q][p] * Wrawt[m2][p]
        gemm_mfma<<<dim3(K2 / 128, LTOT / 128), 256, 0, stream>>>(
            S16, Wrawt, C2, nullptr, LTOT, K2, LTOT);

        output_kernel<<<CC * HH * WW / 256, 256, 0, stream>>>(C2, out + (size_t)bi * CC * HH * WW);
    }
}

// Round 5
// 957.220 us; speedup vs baseline: 3.7227x; 1.0338x over previous
//
#include <hip/hip_runtime.h>

#define CC 128
#define HH 128
#define WW 128
#define DH 64
#define DW 64
#define LTOT 4096          // DH*DW patches / fg positions
#define K1 1152            // CC*3*3
#define K1S 3456           // 3*K1 split-concat K for GEMM1
#define K2 2048            // CC*4*4
#define SCALE_F 10.0f

typedef __attribute__((ext_vector_type(8))) short short8;
typedef __attribute__((ext_vector_type(4))) float f32x4;

// ---- bf16 helpers (RNE) ----
__device__ __forceinline__ unsigned short f2bf(float x) {
    union { float f; unsigned u; } v; v.f = x;
    unsigned r = v.u + 0x7fffu + ((v.u >> 16) & 1u);
    return (unsigned short)(r >> 16);
}
__device__ __forceinline__ float bf2f(unsigned short b) {
    union { unsigned u; float f; } v; v.u = ((unsigned)b) << 16;
    return v.f;
}

#define GLDS16(g, l) __builtin_amdgcn_global_load_lds( \
    (const __attribute__((address_space(1))) void*)(g), \
    (__attribute__((address_space(3))) void*)(l), 16, 0, 0)

// ---------------- im2col + fp32->bf16 split, M-major [p][3456] ----------------
// segments: lo_in_seg1 ? [hi, lo, hi] : [hi, hi, lo]
__global__ __launch_bounds__(256) void im2col_split_kernel(
    const float* __restrict__ src, unsigned short* __restrict__ dst, int lo_in_seg1)
{
    int p = blockIdx.x;                 // 4096 blocks
    int px = p & 63, py = p >> 6;
    size_t base = (size_t)p * K1S;
    for (int k = threadIdx.x; k < K1; k += 256) {
        int dj = k % 3, t = k / 3;
        int di = t % 3, c = t / 3;
        int yy = py + di - 1, xx = px + dj - 1;
        float v = 0.f;
        if (yy >= 0 && yy < DH && xx >= 0 && xx < DW)
            v = src[((size_t)c * HH + (yy << 1)) * WW + (xx << 1)];
        unsigned short hi = f2bf(v);
        unsigned short lo = f2bf(v - bf2f(hi));
        dst[base + k] = hi;
        dst[base + K1 + k]     = lo_in_seg1 ? lo : hi;
        dst[base + 2 * K1 + k] = lo_in_seg1 ? hi : lo;
    }
}

// ---------------- raw 4x4 stride-2 patches of full-res b, transposed: dst[m2][p] bf16 ----------------
__global__ __launch_bounds__(256) void im2col_rawt_kernel(
    const float* __restrict__ src, unsigned short* __restrict__ dst)
{
    int idx = blockIdx.x * 256 + threadIdx.x;   // K2*LTOT threads, p fastest
    int p = idx & (LTOT - 1);
    int m = idx >> 12;
    int px = p & 63, py = p >> 6;
    int ke = m & 3, kd = (m >> 2) & 3, c = m >> 4;
    int yy = 2 * py - 1 + kd, xx = 2 * px - 1 + ke;
    float v = 0.f;
    if (yy >= 0 && yy < HH && xx >= 0 && xx < WW)
        v = src[((size_t)c * HH + yy) * WW + xx];
    dst[idx] = f2bf(v);
}

// ---------------- per-pixel sum of squares over channels (on downsampled b) ----------------
__global__ void ssq_kernel(const float* __restrict__ b, float* __restrict__ ssq) {
    int p = blockIdx.x * blockDim.x + threadIdx.x;     // 4096
    int px = p & 63, py = p >> 6;
    float s = 0.f;
    for (int c = 0; c < CC; ++c) {
        float v = b[((size_t)c * HH + 2 * py) * WW + 2 * px];
        s += v * v;
    }
    ssq[p] = s;
}

// ---------------- patch inverse norm + mask gate ----------------
__global__ void norm_mm_kernel(const float* __restrict__ ssq, const float* __restrict__ mask,
                               float* __restrict__ inv_norm, float* __restrict__ mmv) {
    int p = blockIdx.x * blockDim.x + threadIdx.x;     // 4096
    int px = p & 63, py = p >> 6;
    float s = 0.f, ms = 0.f;
    for (int di = -1; di <= 1; ++di)
        for (int dj = -1; dj <= 1; ++dj) {
            int y = py + di, x = px + dj;
            if (y >= 0 && y < DH && x >= 0 && x < DW) {
                s += ssq[y * 64 + x];
                ms += mask[(size_t)(2 * y) * WW + 2 * x];
            }
        }
    float n = sqrtf(s);
    if (n < 1e-4f) n = 1e-4f;
    inv_norm[p] = 1.f / n;
    mmv[p] = (ms == 0.f) ? 1.f : 0.f;
}

// ---------------- bf16 MFMA GEMM (m97 structure + XOR bank swizzle) ----------------
// A[M][K], B[N][K], C[M][N] fp32. 128x128 tile, BK=32, 4 waves 2x2, 4x4 MFMA 16x16x32.
// LDS slot s (16B chunks) of row m holds global k-chunk s ^ ((m>>1)&3).
// colscale (optional) applies per output column n.
__global__ __launch_bounds__(256) void gemm_mfma(
    const unsigned short* __restrict__ Aop, const unsigned short* __restrict__ Bop,
    float* __restrict__ C, const float* __restrict__ colscale,
    int M, int N, int K)
{
    __shared__ short As[128 * 32];   // [m][k-chunk swizzled] rows of 64B
    __shared__ short Bs[128 * 32];
    int tid = threadIdx.x;
    int wave = tid >> 6, lane = tid & 63;
    int wm = (wave >> 1) * 64;
    int wn = (wave & 1) * 64;
    int bm = blockIdx.y * 128, bn = blockIdx.x * 128;

    int rowS = wave * 32;                 // this wave stages rows [rowS, rowS+32)
    int lrow = lane >> 2;                 // 0..15 within 16-row group
    int lcol = (((lane & 3) ^ ((lrow >> 1) & 3)) * 8);

    f32x4 acc[4][4] = {};

    int quad = lane >> 4;                 // k-slab for MFMA fragments
    int r16 = lane & 15;
    int slotA = (quad ^ ((r16 >> 1) & 3)) * 8;   // un-swizzle at read

    for (int k0 = 0; k0 < K; k0 += 32) {
        const unsigned short* ag = Aop + (size_t)(bm + rowS + lrow) * K + k0 + lcol;
        const unsigned short* bg = Bop + (size_t)(bn + rowS + lrow) * K + k0 + lcol;
        GLDS16(ag,                  As + rowS * 32);
        GLDS16(ag + 16 * (size_t)K, As + (rowS + 16) * 32);
        GLDS16(bg,                  Bs + rowS * 32);
        GLDS16(bg + 16 * (size_t)K, Bs + (rowS + 16) * 32);
        __syncthreads();

        short8 a[4], b[4];
#pragma unroll
        for (int i = 0; i < 4; ++i) {
            a[i] = *(const short8*)&As[(wm + i * 16 + r16) * 32 + slotA];
            b[i] = *(const short8*)&Bs[(wn + i * 16 + r16) * 32 + slotA];
        }
#pragma unroll
        for (int i = 0; i < 4; ++i)
#pragma unroll
            for (int j = 0; j < 4; ++j)
                acc[i][j] = __builtin_amdgcn_mfma_f32_16x16x32_bf16(a[i], b[j], acc[i][j], 0, 0, 0);
        __syncthreads();
    }

    int col = lane & 15, rq = (lane >> 4) * 4;
    float csc[4];
#pragma unroll
    for (int j = 0; j < 4; ++j)
        csc[j] = colscale ? colscale[bn + wn + j * 16 + col] : 1.f;
#pragma unroll
    for (int i = 0; i < 4; ++i) {
#pragma unroll
        for (int r = 0; r < 4; ++r) {
            int m = bm + wm + i * 16 + rq + r;
#pragma unroll
            for (int j = 0; j < 4; ++j)
                C[(size_t)m * N + bn + wn + j * 16 + col] = acc[i][j][r] * csc[j];
        }
    }
}

// ---------------- fused: (fuse2 o fuse1) 9-tap diagonal stencil + row softmax + bf16 write ----------------
// Composite of the two identity-diag 3x3 convs in flat/swap space, exactly matching
// fuse2(fuse1(S)) including flat-index carry at 64-boundaries, then
// softmax over p (row) with mask gating, output bf16 [q][p].
__global__ __launch_bounds__(256) void fused_conv_softmax_kernel(
    const float* __restrict__ S, const float* __restrict__ mmv,
    unsigned short* __restrict__ S16)
{
    __shared__ float redmax[4];
    __shared__ float redsum[4];
    int q = blockIdx.x;
    int t = threadIdx.x;
    int lane = t & 63, wid = t >> 6;

    int rbase = ((q & 63) << 6) | (q >> 6);     // swap(q)
    int rrs[3];
    bool rok[3];
#pragma unroll
    for (int j = 0; j < 3; ++j) {
        int r2 = rbase + (j - 1);
        rok[j] = (r2 >= 0) && (r2 < LTOT);
        rrs[j] = ((r2 & 63) << 6) | ((r2 >> 6) & 63);   // swap(r2)
    }

    float v[16], m[16];
#pragma unroll
    for (int i = 0; i < 16; ++i) {
        int c = t + (i << 8);                   // column p, 0..4095
        int cbase = ((c & 63) << 6) | (c >> 6); // swap(c)
        float s = 0.f;
#pragma unroll
        for (int j = 0; j < 3; ++j) {           // d2 = j-1 (fuse2 order)
            if (!rok[j]) continue;
            int c2 = cbase + (j - 1);
            if (c2 < 0 || c2 >= LTOT) continue;
            int cc = ((c2 & 63) << 6) | (c2 >> 6);  // swap(c2); interior: c + 64*d2
            int rr = rrs[j];
            float tsum = 0.f;
#pragma unroll
            for (int d1 = -1; d1 <= 1; ++d1) {  // fuse1 order
                int a = rr + d1, bcol = cc + d1;
                if (a >= 0 && a < LTOT && bcol >= 0 && bcol < LTOT)
                    tsum += S[(size_t)a * LTOT + bcol];
            }
            s += tsum;
        }
        float mmx = mmv[c];
        m[i] = mmx;
        v[i] = s * mmx * SCALE_F;
    }

    float mx = v[0];
#pragma unroll
    for (int i = 1; i < 16; ++i) mx = fmaxf(mx, v[i]);
#pragma unroll
    for (int o = 32; o; o >>= 1) mx = fmaxf(mx, __shfl_xor(mx, o));
    if (lane == 0) redmax[wid] = mx;
    __syncthreads();
    float gmx = fmaxf(fmaxf(redmax[0], redmax[1]), fmaxf(redmax[2], redmax[3]));

    float s = 0.f;
#pragma unroll
    for (int i = 0; i < 16; ++i) {
        v[i] = __expf(v[i] - gmx);
        s += v[i];
    }
#pragma unroll
    for (int o = 32; o; o >>= 1) s += __shfl_xor(s, o);
    if (lane == 0) redsum[wid] = s;
    __syncthreads();
    float inv = 1.f / (redsum[0] + redsum[1] + redsum[2] + redsum[3]);

    unsigned short* orow = S16 + (size_t)q * LTOT;
#pragma unroll
    for (int i = 0; i < 16; ++i)
        orow[t + (i << 8)] = f2bf(v[i] * inv * m[i]);
}

// ---------------- overlap-add of weighted 4x4 patches (stride 2), /4 ----------------
__global__ void output_kernel(const float* __restrict__ C2, float* __restrict__ out) {
    int idx = blockIdx.x * blockDim.x + threadIdx.x;   // CC*HH*WW
    int x = idx & 127;
    int y = (idx >> 7) & 127;
    int c = idx >> 14;
    int oylo = max(0, (y - 1) >> 1), oyhi = min(63, (y + 1) >> 1);
    int oxlo = max(0, (x - 1) >> 1), oxhi = min(63, (x + 1) >> 1);
    float s = 0.f;
    for (int oy = oylo; oy <= oyhi; ++oy)
        for (int ox = oxlo; ox <= oxhi; ++ox) {
            int kd = y - 2 * oy + 1;
            int ke = x - 2 * ox + 1;
            s += C2[(size_t)(oy * 64 + ox) * K2 + c * 16 + kd * 4 + ke];
        }
    out[idx] = s * 0.25f;
}

extern "C" void kernel_launch(void* const* d_in, const int* in_sizes, int n_in,
                              void* d_out, int out_size, void* d_ws, size_t ws_size,
                              hipStream_t stream) {
    (void)in_sizes; (void)n_in; (void)out_size; (void)ws_size;
    const float* f    = (const float*)d_in[0];
    const float* b    = (const float*)d_in[1];
    const float* mask = (const float*)d_in[2];
    float* out = (float*)d_out;

    char* ws = (char*)d_ws;
    size_t off = 0;
    auto alloc = [&](size_t bytes) -> void* {
        void* p = (void*)(ws + off);
        off += (bytes + 255) & ~(size_t)255;
        return p;
    };
    float* S    = (float*)alloc((size_t)LTOT * LTOT * 4);          // 64 MB: scores [q][p] -> C2
    float* Stmp = (float*)alloc((size_t)LTOT * LTOT * 4);          // 64 MB: S16 (bf16)
    unsigned short* Wsp = (unsigned short*)alloc((size_t)LTOT * K1S * 2);  // 28.3 MB b-patch split [p][k']
    unsigned short* Fsp = (unsigned short*)alloc((size_t)LTOT * K1S * 2);  // 28.3 MB f-patch split [q][k']
    float* ssq  = (float*)alloc(LTOT * 4);
    float* invn = (float*)alloc(LTOT * 4);
    float* mmv  = (float*)alloc(LTOT * 4);

    unsigned short* Wrawt = Wsp;                    // [K2][LTOT] bf16, reuses Wsp after GEMM1
    unsigned short* S16   = (unsigned short*)Stmp;  // [q][p] bf16
    float* C2 = S;                                   // [q][K2] fp32, reuses S after fused softmax

    for (int bi = 0; bi < 2; ++bi) {
        const float* fb = f + (size_t)bi * CC * HH * WW;
        const float* bb = b + (size_t)bi * CC * HH * WW;

        im2col_split_kernel<<<LTOT, 256, 0, stream>>>(bb, Wsp, 1);   // [hi, lo, hi]
        im2col_split_kernel<<<LTOT, 256, 0, stream>>>(fb, Fsp, 0);   // [hi, hi, lo]
        ssq_kernel<<<LTOT / 256, 256, 0, stream>>>(bb, ssq);
        norm_mm_kernel<<<LTOT / 256, 256, 0, stream>>>(ssq, mask, invn, mmv);

        // S[q][p] = invn[p] * sum_k' Fsp[q][k'] * Wsp[p][k']   (split-concat fp32-accurate)
        gemm_mfma<<<dim3(LTOT / 128, LTOT / 128), 256, 0, stream>>>(
            Fsp, Wsp, S, invn, LTOT, LTOT, K1S);

        im2col_rawt_kernel<<<(size_t)K2 * LTOT / 256, 256, 0, stream>>>(bb, Wrawt);

        // fused (fuse2 o fuse1) + softmax + bf16 cast
        fused_conv_softmax_kernel<<<LTOT, 256, 0, stream>>>(S, mmv, S16);

        // C2[q][m2] = sum_p S16[q][p] * Wrawt[m2][p]
        gemm_mfma<<<dim3(K2 / 128, LTOT / 128), 256, 0, stream>>>(
            S16, Wrawt, C2, nullptr, LTOT, K2, LTOT);

        output_kernel<<<CC * HH * WW / 256, 256, 0, stream>>>(C2, out + (size_t)bi * CC * HH * WW);
    }
}

// Round 6
// 818.847 us; speedup vs baseline: 4.3518x; 1.1690x over previous
//
#include <hip/hip_runtime.h>

#define CC 128
#define HH 128
#define WW 128
#define DH 64
#define DW 64
#define LTOT 4096          // DH*DW patches / fg positions
#define K0S 384            // 3*128 split-concat K for the pixel-pair GEMM
#define K2 2048            // CC*4*4
#define SCALE_F 10.0f

typedef __attribute__((ext_vector_type(8))) short short8;
typedef __attribute__((ext_vector_type(4))) float f32x4;

// ---- bf16 helpers (RNE) ----
__device__ __forceinline__ unsigned short f2bf(float x) {
    union { float f; unsigned u; } v; v.f = x;
    unsigned r = v.u + 0x7fffu + ((v.u >> 16) & 1u);
    return (unsigned short)(r >> 16);
}
__device__ __forceinline__ float bf2f(unsigned short b) {
    union { unsigned u; float f; } v; v.u = ((unsigned)b) << 16;
    return v.f;
}

#define GLDS16(g, l) __builtin_amdgcn_global_load_lds( \
    (const __attribute__((address_space(1))) void*)(g), \
    (__attribute__((address_space(3))) void*)(l), 16, 0, 0)

// ---------------- downsample (::2) + fp32->bf16 split, row n = pixel, 384 = [seg0,seg1,seg2]*128ch ----
// b gets [hi, lo, hi], f gets [hi, hi, lo]  =>  products sum to hi*hi + lo*hi + hi*lo
__global__ __launch_bounds__(128) void split_ds_kernel(
    const float* __restrict__ src, unsigned short* __restrict__ dst, int lo_in_seg1)
{
    int n = blockIdx.x;          // 4096 pixels
    int c = threadIdx.x;         // 128 channels
    int ny = n >> 6, nx = n & 63;
    float v = src[((size_t)c * HH + 2 * ny) * WW + 2 * nx];
    unsigned short hi = f2bf(v);
    unsigned short lo = f2bf(v - bf2f(hi));
    unsigned short* drow = dst + (size_t)n * K0S;
    drow[c]       = hi;
    drow[128 + c] = lo_in_seg1 ? lo : hi;
    drow[256 + c] = lo_in_seg1 ? hi : lo;
}

// ---------------- raw 4x4 stride-2 patches of full-res b, transposed: dst[m2][p] bf16 ----------------
__global__ __launch_bounds__(256) void im2col_rawt_kernel(
    const float* __restrict__ src, unsigned short* __restrict__ dst)
{
    int idx = blockIdx.x * 256 + threadIdx.x;   // K2*LTOT threads, p fastest
    int p = idx & (LTOT - 1);
    int m = idx >> 12;
    int px = p & 63, py = p >> 6;
    int ke = m & 3, kd = (m >> 2) & 3, c = m >> 4;
    int yy = 2 * py - 1 + kd, xx = 2 * px - 1 + ke;
    float v = 0.f;
    if (yy >= 0 && yy < HH && xx >= 0 && xx < WW)
        v = src[((size_t)c * HH + yy) * WW + xx];
    dst[idx] = f2bf(v);
}

// ---------------- per-pixel sum of squares over channels (on downsampled b) ----------------
__global__ void ssq_kernel(const float* __restrict__ b, float* __restrict__ ssq) {
    int p = blockIdx.x * blockDim.x + threadIdx.x;     // 4096
    int px = p & 63, py = p >> 6;
    float s = 0.f;
    for (int c = 0; c < CC; ++c) {
        float v = b[((size_t)c * HH + 2 * py) * WW + 2 * px];
        s += v * v;
    }
    ssq[p] = s;
}

// ---------------- patch inverse norm + mask gate ----------------
__global__ void norm_mm_kernel(const float* __restrict__ ssq, const float* __restrict__ mask,
                               float* __restrict__ inv_norm, float* __restrict__ mmv) {
    int p = blockIdx.x * blockDim.x + threadIdx.x;     // 4096
    int px = p & 63, py = p >> 6;
    float s = 0.f, ms = 0.f;
    for (int di = -1; di <= 1; ++di)
        for (int dj = -1; dj <= 1; ++dj) {
            int y = py + di, x = px + dj;
            if (y >= 0 && y < DH && x >= 0 && x < DW) {
                s += ssq[y * 64 + x];
                ms += mask[(size_t)(2 * y) * WW + 2 * x];
            }
        }
    float n = sqrtf(s);
    if (n < 1e-4f) n = 1e-4f;
    inv_norm[p] = 1.f / n;
    mmv[p] = (ms == 0.f) ? 1.f : 0.f;
}

// ---------------- bf16 MFMA GEMM (m97 structure + XOR bank swizzle) ----------------
// A[M][K], B[N][K], C[M][N] fp32. 128x128 tile, BK=32, 4 waves 2x2, 4x4 MFMA 16x16x32.
// LDS slot s (16B chunks) of row m holds global k-chunk s ^ ((m>>1)&3).
// colscale (optional) applies per output column n.
__global__ __launch_bounds__(256) void gemm_mfma(
    const unsigned short* __restrict__ Aop, const unsigned short* __restrict__ Bop,
    float* __restrict__ C, const float* __restrict__ colscale,
    int M, int N, int K)
{
    __shared__ short As[128 * 32];   // [m][k-chunk swizzled] rows of 64B
    __shared__ short Bs[128 * 32];
    int tid = threadIdx.x;
    int wave = tid >> 6, lane = tid & 63;
    int wm = (wave >> 1) * 64;
    int wn = (wave & 1) * 64;
    int bm = blockIdx.y * 128, bn = blockIdx.x * 128;

    int rowS = wave * 32;                 // this wave stages rows [rowS, rowS+32)
    int lrow = lane >> 2;                 // 0..15 within 16-row group
    int lcol = (((lane & 3) ^ ((lrow >> 1) & 3)) * 8);

    f32x4 acc[4][4] = {};

    int quad = lane >> 4;                 // k-slab for MFMA fragments
    int r16 = lane & 15;
    int slotA = (quad ^ ((r16 >> 1) & 3)) * 8;   // un-swizzle at read

    for (int k0 = 0; k0 < K; k0 += 32) {
        const unsigned short* ag = Aop + (size_t)(bm + rowS + lrow) * K + k0 + lcol;
        const unsigned short* bg = Bop + (size_t)(bn + rowS + lrow) * K + k0 + lcol;
        GLDS16(ag,                  As + rowS * 32);
        GLDS16(ag + 16 * (size_t)K, As + (rowS + 16) * 32);
        GLDS16(bg,                  Bs + rowS * 32);
        GLDS16(bg + 16 * (size_t)K, Bs + (rowS + 16) * 32);
        __syncthreads();

        short8 a[4], b[4];
#pragma unroll
        for (int i = 0; i < 4; ++i) {
            a[i] = *(const short8*)&As[(wm + i * 16 + r16) * 32 + slotA];
            b[i] = *(const short8*)&Bs[(wn + i * 16 + r16) * 32 + slotA];
        }
#pragma unroll
        for (int i = 0; i < 4; ++i)
#pragma unroll
            for (int j = 0; j < 4; ++j)
                acc[i][j] = __builtin_amdgcn_mfma_f32_16x16x32_bf16(a[i], b[j], acc[i][j], 0, 0, 0);
        __syncthreads();
    }

    int col = lane & 15, rq = (lane >> 4) * 4;
    float csc[4];
#pragma unroll
    for (int j = 0; j < 4; ++j)
        csc[j] = colscale ? colscale[bn + wn + j * 16 + col] : 1.f;
#pragma unroll
    for (int i = 0; i < 4; ++i) {
#pragma unroll
        for (int r = 0; r < 4; ++r) {
            int m = bm + wm + i * 16 + rq + r;
#pragma unroll
            for (int j = 0; j < 4; ++j)
                C[(size_t)m * N + bn + wn + j * 16 + col] = acc[i][j][r] * csc[j];
        }
    }
}

// ---------------- 9-tap patch stencil: S[q][p] = invn[p] * sum_{u,v} C[q+δ][p+δ], δ=64du+dv ----------------
// Tap (du,dv) valid iff qy+du,qx+dv,py+du,px+dv all in [0,64)  (2D zero-pad of both patches).
__global__ __launch_bounds__(256) void stencil_norm_kernel(
    const float* __restrict__ C, const float* __restrict__ invn,
    float* __restrict__ Sout)
{
    int q = blockIdx.x;
    int t = threadIdx.x;
    int qy = q >> 6, qx = q & 63;
    int px = t & 63;             // px of p = t+256i is i-independent
    int py0 = t >> 6;            // py = py0 + 4i
    float acc[16] = {};
#pragma unroll
    for (int du = -1; du <= 1; ++du) {
        if (qy + du < 0 || qy + du > 63) continue;
#pragma unroll
        for (int dv = -1; dv <= 1; ++dv) {
            if (qx + dv < 0 || qx + dv > 63) continue;
            if (px + dv < 0 || px + dv > 63) continue;
            const float* row = C + (size_t)(q + 64 * du + dv) * LTOT + 64 * du + dv;
#pragma unroll
            for (int i = 0; i < 16; ++i) {
                int py = py0 + 4 * i;
                if (py + du < 0 || py + du > 63) continue;
                acc[i] += row[t + 256 * i];
            }
        }
    }
    float* orow = Sout + (size_t)q * LTOT;
#pragma unroll
    for (int i = 0; i < 16; ++i)
        orow[t + 256 * i] = acc[i] * invn[t + 256 * i];
}

// ---------------- fused: (fuse2 o fuse1) 9-tap diagonal stencil + row softmax + bf16 write ----------------
__global__ __launch_bounds__(256) void fused_conv_softmax_kernel(
    const float* __restrict__ S, const float* __restrict__ mmv,
    unsigned short* __restrict__ S16)
{
    __shared__ float redmax[4];
    __shared__ float redsum[4];
    int q = blockIdx.x;
    int t = threadIdx.x;
    int lane = t & 63, wid = t >> 6;

    int rbase = ((q & 63) << 6) | (q >> 6);     // swap(q)
    int rrs[3];
    bool rok[3];
#pragma unroll
    for (int j = 0; j < 3; ++j) {
        int r2 = rbase + (j - 1);
        rok[j] = (r2 >= 0) && (r2 < LTOT);
        rrs[j] = ((r2 & 63) << 6) | ((r2 >> 6) & 63);   // swap(r2)
    }

    float v[16], m[16];
#pragma unroll
    for (int i = 0; i < 16; ++i) {
        int c = t + (i << 8);                   // column p, 0..4095
        int cbase = ((c & 63) << 6) | (c >> 6); // swap(c)
        float s = 0.f;
#pragma unroll
        for (int j = 0; j < 3; ++j) {           // d2 = j-1 (fuse2 order)
            if (!rok[j]) continue;
            int c2 = cbase + (j - 1);
            if (c2 < 0 || c2 >= LTOT) continue;
            int cc = ((c2 & 63) << 6) | (c2 >> 6);  // swap(c2); interior: c + 64*d2
            int rr = rrs[j];
            float tsum = 0.f;
#pragma unroll
            for (int d1 = -1; d1 <= 1; ++d1) {  // fuse1 order
                int a = rr + d1, bcol = cc + d1;
                if (a >= 0 && a < LTOT && bcol >= 0 && bcol < LTOT)
                    tsum += S[(size_t)a * LTOT + bcol];
            }
            s += tsum;
        }
        float mmx = mmv[c];
        m[i] = mmx;
        v[i] = s * mmx * SCALE_F;
    }

    float mx = v[0];
#pragma unroll
    for (int i = 1; i < 16; ++i) mx = fmaxf(mx, v[i]);
#pragma unroll
    for (int o = 32; o; o >>= 1) mx = fmaxf(mx, __shfl_xor(mx, o));
    if (lane == 0) redmax[wid] = mx;
    __syncthreads();
    float gmx = fmaxf(fmaxf(redmax[0], redmax[1]), fmaxf(redmax[2], redmax[3]));

    float s = 0.f;
#pragma unroll
    for (int i = 0; i < 16; ++i) {
        v[i] = __expf(v[i] - gmx);
        s += v[i];
    }
#pragma unroll
    for (int o = 32; o; o >>= 1) s += __shfl_xor(s, o);
    if (lane == 0) redsum[wid] = s;
    __syncthreads();
    float inv = 1.f / (redsum[0] + redsum[1] + redsum[2] + redsum[3]);

    unsigned short* orow = S16 + (size_t)q * LTOT;
#pragma unroll
    for (int i = 0; i < 16; ++i)
        orow[t + (i << 8)] = f2bf(v[i] * inv * m[i]);
}

// ---------------- overlap-add of weighted 4x4 patches (stride 2), /4 ----------------
__global__ void output_kernel(const float* __restrict__ C2, float* __restrict__ out) {
    int idx = blockIdx.x * blockDim.x + threadIdx.x;   // CC*HH*WW
    int x = idx & 127;
    int y = (idx >> 7) & 127;
    int c = idx >> 14;
    int oylo = max(0, (y - 1) >> 1), oyhi = min(63, (y + 1) >> 1);
    int oxlo = max(0, (x - 1) >> 1), oxhi = min(63, (x + 1) >> 1);
    float s = 0.f;
    for (int oy = oylo; oy <= oyhi; ++oy)
        for (int ox = oxlo; ox <= oxhi; ++ox) {
            int kd = y - 2 * oy + 1;
            int ke = x - 2 * ox + 1;
            s += C2[(size_t)(oy * 64 + ox) * K2 + c * 16 + kd * 4 + ke];
        }
    out[idx] = s * 0.25f;
}

extern "C" void kernel_launch(void* const* d_in, const int* in_sizes, int n_in,
                              void* d_out, int out_size, void* d_ws, size_t ws_size,
                              hipStream_t stream) {
    (void)in_sizes; (void)n_in; (void)out_size; (void)ws_size;
    const float* f    = (const float*)d_in[0];
    const float* b    = (const float*)d_in[1];
    const float* mask = (const float*)d_in[2];
    float* out = (float*)d_out;

    char* ws = (char*)d_ws;
    size_t off = 0;
    auto alloc = [&](size_t bytes) -> void* {
        void* p = (void*)(ws + off);
        off += (bytes + 255) & ~(size_t)255;
        return p;
    };
    float* Cpix = (float*)alloc((size_t)LTOT * LTOT * 4);   // 64 MB: pixel-pair GEMM out -> S16 (bf16)
    float* Sp   = (float*)alloc((size_t)LTOT * LTOT * 4);   // 64 MB: patch-stencil scores -> C2
    unsigned short* Wrawt = (unsigned short*)alloc((size_t)K2 * LTOT * 2);   // 16 MB
    unsigned short* Bsp = (unsigned short*)alloc((size_t)LTOT * K0S * 2);    // 3 MB b-split [p][384]
    unsigned short* Fsp = (unsigned short*)alloc((size_t)LTOT * K0S * 2);    // 3 MB f-split [q][384]
    float* ssq  = (float*)alloc(LTOT * 4);
    float* invn = (float*)alloc(LTOT * 4);
    float* mmv  = (float*)alloc(LTOT * 4);

    unsigned short* S16 = (unsigned short*)Cpix;   // bf16 attention, reuses Cpix after stencil+fuse
    float* C2 = Sp;                                 // [q][K2] fp32, reuses Sp after fused softmax

    for (int bi = 0; bi < 2; ++bi) {
        const float* fb = f + (size_t)bi * CC * HH * WW;
        const float* bb = b + (size_t)bi * CC * HH * WW;

        split_ds_kernel<<<LTOT, 128, 0, stream>>>(bb, Bsp, 1);   // [hi, lo, hi]
        split_ds_kernel<<<LTOT, 128, 0, stream>>>(fb, Fsp, 0);   // [hi, hi, lo]
        ssq_kernel<<<LTOT / 256, 256, 0, stream>>>(bb, ssq);
        norm_mm_kernel<<<LTOT / 256, 256, 0, stream>>>(ssq, mask, invn, mmv);

        // Cpix[q][p] = sum_c fd[c][q]*bd[c][p]   (split-concat fp32-accurate, K=384)
        gemm_mfma<<<dim3(LTOT / 128, LTOT / 128), 256, 0, stream>>>(
            Fsp, Bsp, Cpix, nullptr, LTOT, LTOT, K0S);

        // patch inner products: 9-tap diagonal stencil + invn column scale
        stencil_norm_kernel<<<LTOT, 256, 0, stream>>>(Cpix, invn, Sp);

        im2col_rawt_kernel<<<(size_t)K2 * LTOT / 256, 256, 0, stream>>>(bb, Wrawt);

        // fused (fuse2 o fuse1) + softmax + bf16 cast
        fused_conv_softmax_kernel<<<LTOT, 256, 0, stream>>>(Sp, mmv, S16);

        // C2[q][m2] = sum_p S16[q][p] * Wrawt[m2][p]
        gemm_mfma<<<dim3(K2 / 128, LTOT / 128), 256, 0, stream>>>(
            S16, Wrawt, C2, nullptr, LTOT, K2, LTOT);

        output_kernel<<<CC * HH * WW / 256, 256, 0, stream>>>(C2, out + (size_t)bi * CC * HH * WW);
    }
}

// Round 7
// 705.084 us; speedup vs baseline: 5.0540x; 1.1613x over previous
//
#include <hip/hip_runtime.h>

#define CC 128
#define HH 128
#define WW 128
#define DH 64
#define DW 64
#define LTOT 4096          // DH*DW patches / fg positions
#define K0S 384            // 3*128 split-concat K for the pixel-pair GEMM
#define K2 2048            // CC*4*4
#define SCALE_F 10.0f

typedef __attribute__((ext_vector_type(8))) short short8;
typedef __attribute__((ext_vector_type(4))) float f32x4;

// ---- bf16 helpers (RNE) ----
__device__ __forceinline__ unsigned short f2bf(float x) {
    union { float f; unsigned u; } v; v.f = x;
    unsigned r = v.u + 0x7fffu + ((v.u >> 16) & 1u);
    return (unsigned short)(r >> 16);
}
__device__ __forceinline__ float bf2f(unsigned short b) {
    union { unsigned u; float f; } v; v.u = ((unsigned)b) << 16;
    return v.f;
}

#define GLDS16(g, l) __builtin_amdgcn_global_load_lds( \
    (const __attribute__((address_space(1))) void*)(g), \
    (__attribute__((address_space(3))) void*)(l), 16, 0, 0)

// ---------------- downsample (::2) + fp32->bf16 split, row n = pixel, 384 = [seg0,seg1,seg2]*128ch ----
// b gets [hi, lo, hi], f gets [hi, hi, lo]  =>  products sum to hi*hi + lo*hi + hi*lo
__global__ __launch_bounds__(128) void split_ds_kernel(
    const float* __restrict__ src, unsigned short* __restrict__ dst, int lo_in_seg1)
{
    int n = blockIdx.x;          // 4096 pixels
    int c = threadIdx.x;         // 128 channels
    int ny = n >> 6, nx = n & 63;
    float v = src[((size_t)c * HH + 2 * ny) * WW + 2 * nx];
    unsigned short hi = f2bf(v);
    unsigned short lo = f2bf(v - bf2f(hi));
    unsigned short* drow = dst + (size_t)n * K0S;
    drow[c]       = hi;
    drow[128 + c] = lo_in_seg1 ? lo : hi;
    drow[256 + c] = lo_in_seg1 ? hi : lo;
}

// ---------------- raw 4x4 stride-2 patches of full-res b, transposed: dst[m2][p] bf16 ----------------
__global__ __launch_bounds__(256) void im2col_rawt_kernel(
    const float* __restrict__ src, unsigned short* __restrict__ dst)
{
    int idx = blockIdx.x * 256 + threadIdx.x;   // K2*LTOT threads, p fastest
    int p = idx & (LTOT - 1);
    int m = idx >> 12;
    int px = p & 63, py = p >> 6;
    int ke = m & 3, kd = (m >> 2) & 3, c = m >> 4;
    int yy = 2 * py - 1 + kd, xx = 2 * px - 1 + ke;
    float v = 0.f;
    if (yy >= 0 && yy < HH && xx >= 0 && xx < WW)
        v = src[((size_t)c * HH + yy) * WW + xx];
    dst[idx] = f2bf(v);
}

// ---------------- per-pixel sum of squares over channels (on downsampled b) ----------------
__global__ void ssq_kernel(const float* __restrict__ b, float* __restrict__ ssq) {
    int p = blockIdx.x * blockDim.x + threadIdx.x;     // 4096
    int px = p & 63, py = p >> 6;
    float s = 0.f;
    for (int c = 0; c < CC; ++c) {
        float v = b[((size_t)c * HH + 2 * py) * WW + 2 * px];
        s += v * v;
    }
    ssq[p] = s;
}

// ---------------- patch inverse norm + mask gate ----------------
__global__ void norm_mm_kernel(const float* __restrict__ ssq, const float* __restrict__ mask,
                               float* __restrict__ inv_norm, float* __restrict__ mmv) {
    int p = blockIdx.x * blockDim.x + threadIdx.x;     // 4096
    int px = p & 63, py = p >> 6;
    float s = 0.f, ms = 0.f;
    for (int di = -1; di <= 1; ++di)
        for (int dj = -1; dj <= 1; ++dj) {
            int y = py + di, x = px + dj;
            if (y >= 0 && y < DH && x >= 0 && x < DW) {
                s += ssq[y * 64 + x];
                ms += mask[(size_t)(2 * y) * WW + 2 * x];
            }
        }
    float n = sqrtf(s);
    if (n < 1e-4f) n = 1e-4f;
    inv_norm[p] = 1.f / n;
    mmv[p] = (ms == 0.f) ? 1.f : 0.f;
}

// ---------------- bf16 MFMA GEMM (m97 structure + XOR bank swizzle) ----------------
// A[M][K], B[N][K], C[M][N] fp32. 128x128 tile, BK=32, 4 waves 2x2, 4x4 MFMA 16x16x32.
// LDS slot s (16B chunks) of row m holds global k-chunk s ^ ((m>>1)&3).
// colscale (optional) applies per output column n.
__global__ __launch_bounds__(256) void gemm_mfma(
    const unsigned short* __restrict__ Aop, const unsigned short* __restrict__ Bop,
    float* __restrict__ C, const float* __restrict__ colscale,
    int M, int N, int K)
{
    __shared__ short As[128 * 32];   // [m][k-chunk swizzled] rows of 64B
    __shared__ short Bs[128 * 32];
    int tid = threadIdx.x;
    int wave = tid >> 6, lane = tid & 63;
    int wm = (wave >> 1) * 64;
    int wn = (wave & 1) * 64;
    int bm = blockIdx.y * 128, bn = blockIdx.x * 128;

    int rowS = wave * 32;                 // this wave stages rows [rowS, rowS+32)
    int lrow = lane >> 2;                 // 0..15 within 16-row group
    int lcol = (((lane & 3) ^ ((lrow >> 1) & 3)) * 8);

    f32x4 acc[4][4] = {};

    int quad = lane >> 4;                 // k-slab for MFMA fragments
    int r16 = lane & 15;
    int slotA = (quad ^ ((r16 >> 1) & 3)) * 8;   // un-swizzle at read

    for (int k0 = 0; k0 < K; k0 += 32) {
        const unsigned short* ag = Aop + (size_t)(bm + rowS + lrow) * K + k0 + lcol;
        const unsigned short* bg = Bop + (size_t)(bn + rowS + lrow) * K + k0 + lcol;
        GLDS16(ag,                  As + rowS * 32);
        GLDS16(ag + 16 * (size_t)K, As + (rowS + 16) * 32);
        GLDS16(bg,                  Bs + rowS * 32);
        GLDS16(bg + 16 * (size_t)K, Bs + (rowS + 16) * 32);
        __syncthreads();

        short8 a[4], b[4];
#pragma unroll
        for (int i = 0; i < 4; ++i) {
            a[i] = *(const short8*)&As[(wm + i * 16 + r16) * 32 + slotA];
            b[i] = *(const short8*)&Bs[(wn + i * 16 + r16) * 32 + slotA];
        }
#pragma unroll
        for (int i = 0; i < 4; ++i)
#pragma unroll
            for (int j = 0; j < 4; ++j)
                acc[i][j] = __builtin_amdgcn_mfma_f32_16x16x32_bf16(a[i], b[j], acc[i][j], 0, 0, 0);
        __syncthreads();
    }

    int col = lane & 15, rq = (lane >> 4) * 4;
    float csc[4];
#pragma unroll
    for (int j = 0; j < 4; ++j)
        csc[j] = colscale ? colscale[bn + wn + j * 16 + col] : 1.f;
#pragma unroll
    for (int i = 0; i < 4; ++i) {
#pragma unroll
        for (int r = 0; r < 4; ++r) {
            int m = bm + wm + i * 16 + rq + r;
#pragma unroll
            for (int j = 0; j < 4; ++j)
                C[(size_t)m * N + bn + wn + j * 16 + col] = acc[i][j][r] * csc[j];
        }
    }
}

// ---------------- 9-tap patch stencil: S[q][p] = invn[p] * sum_{u,v} C[q+δ][p+δ], δ=64du+dv ----------------
// Tap (du,dv) valid iff qy+du,qx+dv,py+du,px+dv all in [0,64)  (2D zero-pad of both patches).
// XCD swizzle: blocks with equal (blk&7) share an XCD (round-robin dispatch) and own a
// contiguous 512-row q range -> tap halo stays resident in that XCD's 4MiB L2.
__global__ __launch_bounds__(256) void stencil_norm_kernel(
    const float* __restrict__ C, const float* __restrict__ invn,
    float* __restrict__ Sout)
{
    int blk = blockIdx.x;
    int q = ((blk & 7) << 9) | (blk >> 3);
    int t = threadIdx.x;
    int qy = q >> 6, qx = q & 63;
    int px = t & 63;             // px of p = t+256i is i-independent
    int py0 = t >> 6;            // py = py0 + 4i
    float acc[16] = {};
#pragma unroll
    for (int du = -1; du <= 1; ++du) {
        if (qy + du < 0 || qy + du > 63) continue;
#pragma unroll
        for (int dv = -1; dv <= 1; ++dv) {
            if (qx + dv < 0 || qx + dv > 63) continue;
            if (px + dv < 0 || px + dv > 63) continue;
            const float* row = C + (size_t)(q + 64 * du + dv) * LTOT + 64 * du + dv;
#pragma unroll
            for (int i = 0; i < 16; ++i) {
                int py = py0 + 4 * i;
                if (py + du < 0 || py + du > 63) continue;
                acc[i] += row[t + 256 * i];
            }
        }
    }
    float* orow = Sout + (size_t)q * LTOT;
#pragma unroll
    for (int i = 0; i < 16; ++i)
        orow[t + 256 * i] = acc[i] * invn[t + 256 * i];
}

// ---------------- fused: (fuse2 o fuse1) 9-tap diagonal stencil + row softmax + bf16 write ----------------
// Same XCD swizzle as stencil_norm (tap rows are q +/- {0,1,63,64,65}).
__global__ __launch_bounds__(256) void fused_conv_softmax_kernel(
    const float* __restrict__ S, const float* __restrict__ mmv,
    unsigned short* __restrict__ S16)
{
    __shared__ float redmax[4];
    __shared__ float redsum[4];
    int blk = blockIdx.x;
    int q = ((blk & 7) << 9) | (blk >> 3);
    int t = threadIdx.x;
    int lane = t & 63, wid = t >> 6;

    int rbase = ((q & 63) << 6) | (q >> 6);     // swap(q)
    int rrs[3];
    bool rok[3];
#pragma unroll
    for (int j = 0; j < 3; ++j) {
        int r2 = rbase + (j - 1);
        rok[j] = (r2 >= 0) && (r2 < LTOT);
        rrs[j] = ((r2 & 63) << 6) | ((r2 >> 6) & 63);   // swap(r2)
    }

    float v[16], m[16];
#pragma unroll
    for (int i = 0; i < 16; ++i) {
        int c = t + (i << 8);                   // column p, 0..4095
        int cbase = ((c & 63) << 6) | (c >> 6); // swap(c)
        float s = 0.f;
#pragma unroll
        for (int j = 0; j < 3; ++j) {           // d2 = j-1 (fuse2 order)
            if (!rok[j]) continue;
            int c2 = cbase + (j - 1);
            if (c2 < 0 || c2 >= LTOT) continue;
            int cc = ((c2 & 63) << 6) | (c2 >> 6);  // swap(c2); interior: c + 64*d2
            int rr = rrs[j];
            float tsum = 0.f;
#pragma unroll
            for (int d1 = -1; d1 <= 1; ++d1) {  // fuse1 order
                int a = rr + d1, bcol = cc + d1;
                if (a >= 0 && a < LTOT && bcol >= 0 && bcol < LTOT)
                    tsum += S[(size_t)a * LTOT + bcol];
            }
            s += tsum;
        }
        float mmx = mmv[c];
        m[i] = mmx;
        v[i] = s * mmx * SCALE_F;
    }

    float mx = v[0];
#pragma unroll
    for (int i = 1; i < 16; ++i) mx = fmaxf(mx, v[i]);
#pragma unroll
    for (int o = 32; o; o >>= 1) mx = fmaxf(mx, __shfl_xor(mx, o));
    if (lane == 0) redmax[wid] = mx;
    __syncthreads();
    float gmx = fmaxf(fmaxf(redmax[0], redmax[1]), fmaxf(redmax[2], redmax[3]));

    float s = 0.f;
#pragma unroll
    for (int i = 0; i < 16; ++i) {
        v[i] = __expf(v[i] - gmx);
        s += v[i];
    }
#pragma unroll
    for (int o = 32; o; o >>= 1) s += __shfl_xor(s, o);
    if (lane == 0) redsum[wid] = s;
    __syncthreads();
    float inv = 1.f / (redsum[0] + redsum[1] + redsum[2] + redsum[3]);

    unsigned short* orow = S16 + (size_t)q * LTOT;
#pragma unroll
    for (int i = 0; i < 16; ++i)
        orow[t + (i << 8)] = f2bf(v[i] * inv * m[i]);
}

// ---------------- overlap-add of weighted 4x4 patches (stride 2), /4 ----------------
__global__ void output_kernel(const float* __restrict__ C2, float* __restrict__ out) {
    int idx = blockIdx.x * blockDim.x + threadIdx.x;   // CC*HH*WW
    int x = idx & 127;
    int y = (idx >> 7) & 127;
    int c = idx >> 14;
    int oylo = max(0, (y - 1) >> 1), oyhi = min(63, (y + 1) >> 1);
    int oxlo = max(0, (x - 1) >> 1), oxhi = min(63, (x + 1) >> 1);
    float s = 0.f;
    for (int oy = oylo; oy <= oyhi; ++oy)
        for (int ox = oxlo; ox <= oxhi; ++ox) {
            int kd = y - 2 * oy + 1;
            int ke = x - 2 * ox + 1;
            s += C2[(size_t)(oy * 64 + ox) * K2 + c * 16 + kd * 4 + ke];
        }
    out[idx] = s * 0.25f;
}

extern "C" void kernel_launch(void* const* d_in, const int* in_sizes, int n_in,
                              void* d_out, int out_size, void* d_ws, size_t ws_size,
                              hipStream_t stream) {
    (void)in_sizes; (void)n_in; (void)out_size; (void)ws_size;
    const float* f    = (const float*)d_in[0];
    const float* b    = (const float*)d_in[1];
    const float* mask = (const float*)d_in[2];
    float* out = (float*)d_out;

    char* ws = (char*)d_ws;
    size_t off = 0;
    auto alloc = [&](size_t bytes) -> void* {
        void* p = (void*)(ws + off);
        off += (bytes + 255) & ~(size_t)255;
        return p;
    };
    float* Cpix = (float*)alloc((size_t)LTOT * LTOT * 4);   // 64 MB: pixel-pair GEMM out -> S16 (bf16)
    float* Sp   = (float*)alloc((size_t)LTOT * LTOT * 4);   // 64 MB: patch-stencil scores -> C2
    unsigned short* Wrawt = (unsigned short*)alloc((size_t)K2 * LTOT * 2);   // 16 MB
    unsigned short* Bsp = (unsigned short*)alloc((size_t)LTOT * K0S * 2);    // 3 MB b-split [p][384]
    unsigned short* Fsp = (unsigned short*)alloc((size_t)LTOT * K0S * 2);    // 3 MB f-split [q][384]
    float* ssq  = (float*)alloc(LTOT * 4);
    float* invn = (float*)alloc(LTOT * 4);
    float* mmv  = (float*)alloc(LTOT * 4);

    unsigned short* S16 = (unsigned short*)Cpix;   // bf16 attention, reuses Cpix after stencil+fuse
    float* C2 = Sp;                                 // [q][K2] fp32, reuses Sp after fused softmax

    for (int bi = 0; bi < 2; ++bi) {
        const float* fb = f + (size_t)bi * CC * HH * WW;
        const float* bb = b + (size_t)bi * CC * HH * WW;

        split_ds_kernel<<<LTOT, 128, 0, stream>>>(bb, Bsp, 1);   // [hi, lo, hi]
        split_ds_kernel<<<LTOT, 128, 0, stream>>>(fb, Fsp, 0);   // [hi, hi, lo]
        ssq_kernel<<<LTOT / 256, 256, 0, stream>>>(bb, ssq);
        norm_mm_kernel<<<LTOT / 256, 256, 0, stream>>>(ssq, mask, invn, mmv);

        // Cpix[q][p] = sum_c fd[c][q]*bd[c][p]   (split-concat fp32-accurate, K=384)
        gemm_mfma<<<dim3(LTOT / 128, LTOT / 128), 256, 0, stream>>>(
            Fsp, Bsp, Cpix, nullptr, LTOT, LTOT, K0S);

        // patch inner products: 9-tap diagonal stencil + invn column scale
        stencil_norm_kernel<<<LTOT, 256, 0, stream>>>(Cpix, invn, Sp);

        im2col_rawt_kernel<<<(size_t)K2 * LTOT / 256, 256, 0, stream>>>(bb, Wrawt);

        // fused (fuse2 o fuse1) + softmax + bf16 cast
        fused_conv_softmax_kernel<<<LTOT, 256, 0, stream>>>(Sp, mmv, S16);

        // C2[q][m2] = sum_p S16[q][p] * Wrawt[m2][p]
        gemm_mfma<<<dim3(K2 / 128, LTOT / 128), 256, 0, stream>>>(
            S16, Wrawt, C2, nullptr, LTOT, K2, LTOT);

        output_kernel<<<CC * HH * WW / 256, 256, 0, stream>>>(C2, out + (size_t)bi * CC * HH * WW);
    }
}